// Round 12
// baseline (618.313 us; speedup 1.0000x reference)
//
#include <hip/hip_runtime.h>
#include <hip/hip_bf16.h>

// SplineCNN block.
// Edge records (32 B, CSR(dst) order): d0=src, d1=wx[0..3], d2=wx[4..7],
//   d3..d6 = basis[0..7] bf16 pairs.
// conv1/conv2: fused S-scheme, 1024 thr / 16 nodes, wave-per-node.
//   Phase 1 (round-9 proven shape): lane = channel c (32) x bin-half bh (2),
//   plain scalar LDS += (2-way conflicts = free). Metadata: 64-record batches,
//   v_readlane of ALL SIX words then per-lane bh select (no DS-pipe shfl,
//   no source-lane-select bug). x-gathers SGPR-based, batched 8-deep.
//   Phase 2: MFMA GEMM, SPITCH=897 scalar A-reads (conflict-free).
//   conv2 epilogue folds BN-stats atomics. h3_build computes BN coef inline.
// conv3: Z-scheme dense MFMA GEMM + readlane gather-aggregate.

#define EPS 1e-5f
#define MAXN 50176
#define MAXE 401408
#define SPITCH 897   // mod 32 == 1 -> phase-2 scalar A-reads 2 lanes/bank (free)

typedef __attribute__((ext_vector_type(8))) short short8;
typedef __attribute__((ext_vector_type(4))) float floatx4;

__device__ int             g_deg[MAXN];
__device__ int             g_offs[MAXN + 1];
__device__ int             g_cursor[MAXN];
__device__ uint4           g_emeta[MAXE * 2];
__device__ __align__(16) __hip_bfloat16 g_h0[MAXN * 32];
__device__ __align__(16) __hip_bfloat16 g_h1[MAXN * 32];
__device__ __align__(16) __hip_bfloat16 g_h2[MAXN * 64];
__device__ __align__(16) __hip_bfloat16 g_h3[MAXN * 96];
__device__ __align__(16) __hip_bfloat16 g_Z[(size_t)MAXN * 896];
__device__ __align__(16) __hip_bfloat16 g_Wp1[28672];
__device__ __align__(16) __hip_bfloat16 g_Wp2[57344];
__device__ __align__(16) __hip_bfloat16 g_Wp3[86016];
__device__ float           g_stats[128];
__device__ int             g_isbf16;

__device__ __forceinline__ float loadf(const void* p, int i, bool bf)
{
    return bf ? (float)((const __hip_bfloat16*)p)[i] : ((const float*)p)[i];
}
__device__ __forceinline__ float bf16f(unsigned int u)
{
    return __uint_as_float(u << 16);
}

// ---------------- K1: zero-init scratch + wire dtype detect ----------------
__global__ void init_detect(const unsigned int* __restrict__ x, int n)
{
    int i = blockIdx.x * blockDim.x + threadIdx.x;
    if (blockIdx.x == 0 && threadIdx.x < 64) {
        int lane = threadIdx.x;
        int cnt = 0;
        for (int k = lane; k < 256; k += 64) {
            unsigned int lo = x[k] & 0xFFFFu;
            int ex = (int)((lo >> 7) & 0xFFu);
            if (lo == 0u || (ex >= 96 && ex <= 140)) cnt++;
        }
#pragma unroll
        for (int o = 1; o < 64; o <<= 1) cnt += __shfl_xor(cnt, o, 64);
        if (lane == 0) g_isbf16 = (cnt >= 200) ? 1 : 0;
    }
    if (i < n) { g_deg[i] = 0; g_cursor[i] = 0; }
    if (i < 128) g_stats[i] = 0.0f;
}

// ---------------- weight pack helpers (device) ----------------
template <int COUT>
__device__ __forceinline__ void prep_ws_dev(const void* W, const void* root,
                                            __hip_bfloat16* Wp, int t, bool bf)
{
    int j = t & 7;
    int lane = (t >> 3) & 63;
    int rest = t >> 9;
    int kk = rest % 28;
    int nt = rest / 28;
    int k = kk * 32 + (lane >> 4) * 8 + j;
    int o = nt * 16 + (lane & 15);
    float v = (k < 864) ? loadf(W, k * COUT + o, bf)
                        : loadf(root, (k - 864) * COUT + o, bf);
    Wp[t] = __float2bfloat16(v);
}

__device__ __forceinline__ void prep_w3_dev(const void* W, const void* root,
                                            __hip_bfloat16* Wp, int t, bool bf)
{
    const int KB = 3;   // KPAD=96
    int j = t & 7;
    int lane = (t >> 3) & 63;
    int rest = t >> 9;
    int kk = rest % KB;
    int nt = rest / KB;
    int k = kk * 32 + (lane >> 4) * 8 + j;
    int ncol = nt * 16 + (lane & 15);
    int kw = ncol >> 5;          // /32
    int o = ncol & 31;
    float v = 0.0f;
    if (k < 67)
        v = (kw < 27) ? loadf(W, (kw * 67 + k) * 32 + o, bf)
                      : loadf(root, k * 32 + o, bf);
    Wp[t] = __float2bfloat16(v);
}

// ---------------- K2: degree count + cast x + pack all weights ----------------
__global__ void misc_kernel(const int* __restrict__ dst, const void* __restrict__ x,
                            const void* W1, const void* r1,
                            const void* W2, const void* r2,
                            const void* W3, const void* r3, int E, int N)
{
    int t = blockIdx.x * blockDim.x + threadIdx.x;
    const bool bf = (g_isbf16 != 0);
    if (t < E) { atomicAdd(&g_deg[dst[t]], 1); return; }
    t -= E;
    int nx = N * 32;
    if (t < nx) { g_h0[t] = __float2bfloat16(loadf(x, t, bf)); return; }
    t -= nx;
    if (t < 28672) { prep_ws_dev<32>(W1, r1, g_Wp1, t, bf); return; }
    t -= 28672;
    if (t < 57344) { prep_ws_dev<64>(W2, r2, g_Wp2, t, bf); return; }
    t -= 57344;
    if (t < 86016) { prep_w3_dev(W3, r3, g_Wp3, t, bf); return; }
}

// ---------------- K3: exclusive scan (single block) ----------------
__global__ void scan_kernel(int n, int chunk)
{
    __shared__ int buf[1024];
    int tid = threadIdx.x;
    int begin = tid * chunk;
    int end = begin + chunk; if (end > n) end = n;
    int s = 0;
    for (int i = begin; i < end; ++i) s += g_deg[i];
    buf[tid] = s;
    __syncthreads();
    for (int o = 1; o < 1024; o <<= 1) {
        int t = (tid >= o) ? buf[tid - o] : 0;
        __syncthreads();
        buf[tid] += t;
        __syncthreads();
    }
    int base = buf[tid] - s;
    for (int i = begin; i < end; ++i) { g_offs[i] = base; base += g_deg[i]; }
    if (tid == 1023) g_offs[n] = buf[1023];
}

// ---------------- K4: basis + CSR fill (32-B edge records) ----------------
__global__ void basis_fill(const void* __restrict__ attr,
                           const int* __restrict__ src,
                           const int* __restrict__ dst, int E)
{
    int e = blockIdx.x * blockDim.x + threadIdx.x;
    if (e >= E) return;
    const bool bf = (g_isbf16 != 0);
    float f[3];
    int lo[3];
#pragma unroll
    for (int d = 0; d < 3; ++d) {
        float a = loadf(attr, e * 3 + d, bf);
        float s = a * 3.0f;
        float l = floorf(s);
        lo[d] = (int)l;
        f[d] = s - l;
    }
    const int p3[3] = {1, 3, 9};
    unsigned int wxp0 = 0, wxp1 = 0;
    unsigned short bb[8];
#pragma unroll
    for (int b = 0; b < 8; ++b) {
        float w = 1.0f;
        int id = 0;
#pragma unroll
        for (int d = 0; d < 3; ++d) {
            int bit = (b >> d) & 1;
            w *= bit ? f[d] : (1.0f - f[d]);
            id += ((lo[d] + bit) % 3) * p3[d];
        }
        if (b < 4) wxp0 |= (unsigned int)id << (8 * b);
        else       wxp1 |= (unsigned int)id << (8 * (b - 4));
        union { __hip_bfloat16 h; unsigned short u; } cv;
        cv.h = __float2bfloat16(w);
        bb[b] = cv.u;
    }
    int d = dst[e];
    int p = atomicAdd(&g_cursor[d], 1);
    int slot = g_offs[d] + p;
    g_emeta[slot * 2] = make_uint4((unsigned int)src[e], wxp0, wxp1,
                                   (unsigned int)bb[0] | ((unsigned int)bb[1] << 16));
    g_emeta[slot * 2 + 1] = make_uint4(
        (unsigned int)bb[2] | ((unsigned int)bb[3] << 16),
        (unsigned int)bb[4] | ((unsigned int)bb[5] << 16),
        (unsigned int)bb[6] | ((unsigned int)bb[7] << 16), 0u);
}

// ---------------- fused conv (CIN=32) ----------------
// IN_SEL: 0 = g_h0, 1 = g_h1.  OUT_SEL: 1 = g_h1 (+ELU), 2 = g_h2 (+BN stats).
template <int COUT, bool ELU, int IN_SEL, int OUT_SEL>
__global__ __launch_bounds__(1024, 8) void fused_conv(const void* __restrict__ bias,
                                                      int N)
{
    __shared__ float S[16 * SPITCH];
    int tid = threadIdx.x, wid = tid >> 6, lane = tid & 63;
    int nbase = blockIdx.x * 16;
    const bool bf = (g_isbf16 != 0);
    const unsigned short* xptr = (IN_SEL == 0) ? (const unsigned short*)g_h0
                                               : (const unsigned short*)g_h1;
    const __hip_bfloat16* Wp = (COUT == 32) ? g_Wp1 : g_Wp2;

    // hoisted: offs + first 64-record batch overlaps the S zero-init
    int n = nbase + wid;
    int e0 = 0, e1 = 0;
    uint4 p0 = make_uint4(0, 0, 0, 0), p1 = make_uint4(0, 0, 0, 0);
    if (n < N) {
        e0 = g_offs[n]; e1 = g_offs[n + 1];
        int cnt0 = e1 - e0; if (cnt0 > 64) cnt0 = 64;
        if (lane < cnt0) {
            size_t le = (size_t)(e0 + lane) * 2;
            p0 = g_emeta[le];
            p1 = g_emeta[le + 1];
        }
    }

    for (int i = tid; i < 16 * SPITCH; i += 1024) S[i] = 0.0f;
    __syncthreads();

    // ---- phase 1: wave wid aggregates its node; lane = (channel c, bin-half bh) ----
    if (n < N) {
        float* Srow = S + wid * SPITCH;
        int c = lane & 31, bh = lane >> 5;
        float xs = bf16f(xptr[n * 32 + c]);
        if (bh == 0) Srow[864 + c] = xs;        // self-x -> root columns
        for (int base = e0; base < e1; base += 64) {
            int cnt = e1 - base; if (cnt > 64) cnt = 64;
            uint4 r0, r1;
            if (base == e0) { r0 = p0; r1 = p1; }
            else {
                r0 = make_uint4(0, 0, 0, 0); r1 = make_uint4(0, 0, 0, 0);
                if (lane < cnt) {
                    size_t le = (size_t)(base + lane) * 2;
                    r0 = g_emeta[le];
                    r1 = g_emeta[le + 1];
                }
            }
            for (int j0 = 0; j0 < cnt; j0 += 8) {
                int jn = cnt - j0; if (jn > 8) jn = 8;
                unsigned short xv[8];
#pragma unroll
                for (int j = 0; j < 8; ++j) {
                    if (j < jn) {
                        int sn = __builtin_amdgcn_readlane((int)r0.x, j0 + j);
                        xv[j] = xptr[(size_t)sn * 32 + c];
                    }
                }
#pragma unroll
                for (int j = 0; j < 8; ++j) {
                    if (j >= jn) break;
                    int jj = j0 + j;
                    // uniform readlane of ALL words, THEN per-lane bh select
                    unsigned int w03 = (unsigned int)__builtin_amdgcn_readlane((int)r0.y, jj);
                    unsigned int w47 = (unsigned int)__builtin_amdgcn_readlane((int)r0.z, jj);
                    unsigned int b01 = (unsigned int)__builtin_amdgcn_readlane((int)r0.w, jj);
                    unsigned int b23 = (unsigned int)__builtin_amdgcn_readlane((int)r1.x, jj);
                    unsigned int b45 = (unsigned int)__builtin_amdgcn_readlane((int)r1.y, jj);
                    unsigned int b67 = (unsigned int)__builtin_amdgcn_readlane((int)r1.z, jj);
                    unsigned int w4 = bh ? w47 : w03;
                    unsigned int ba = bh ? b45 : b01;
                    unsigned int bv = bh ? b67 : b23;
                    float xf = bf16f(xv[j]);
#pragma unroll
                    for (int bi = 0; bi < 4; ++bi) {
                        int wxv = (int)((w4 >> (8 * bi)) & 0xFFu);
                        unsigned int bbits = (((bi & 2) ? bv : ba) >> (16 * (bi & 1))) & 0xFFFFu;
                        Srow[wxv * 32 + c] += bf16f(bbits) * xf;
                    }
                }
            }
        }
        // scale spline bins by 1/deg (root cols 864..895 untouched)
        int deg = e1 - e0;
        float inv = 1.0f / (float)(deg < 1 ? 1 : deg);
        for (int cc = lane; cc < 864; cc += 64) Srow[cc] *= inv;
    }
    __syncthreads();

    // ---- phase 2: wave w = col-tile w of GEMM 16 x 896 @ 896 x COUT ----
    if (wid * 16 < COUT) {
        int m = lane & 15, quad = lane >> 4;
        const float* Abase = S + m * SPITCH + quad * 8;
        floatx4 acc = {};
#pragma unroll
        for (int kk = 0; kk < 28; ++kk) {
            union { __hip_bfloat16 h[8]; short8 v; } u;
            const float* ap = Abase + kk * 32;
#pragma unroll
            for (int j = 0; j < 8; ++j) u.h[j] = __float2bfloat16(ap[j]);
            const short* bp = (const short*)Wp +
                ((size_t)(wid * 28 + kk) * 64 + lane) * 8;
            short8 b = *(const short8*)bp;
            acc = __builtin_amdgcn_mfma_f32_16x16x32_bf16(u.v, b, acc, 0, 0, 0);
        }
        int o = wid * 16 + (lane & 15);
        float bval = loadf(bias, o, bf);
        float s1 = 0.0f, s2 = 0.0f;
#pragma unroll
        for (int r = 0; r < 4; ++r) {
            int slot = quad * 4 + r;
            int nn = nbase + slot;
            if (nn >= N) continue;
            float v = acc[r] + bval;
            if (ELU) v = v > 0.0f ? v : expm1f(v);
            if (OUT_SEL == 1) g_h1[nn * 32 + o] = __float2bfloat16(v);
            else              g_h2[nn * 64 + o] = __float2bfloat16(v);
            s1 += v; s2 += v * v;
        }
        if (OUT_SEL == 2) {
            s1 += __shfl_xor(s1, 16, 64); s1 += __shfl_xor(s1, 32, 64);
            s2 += __shfl_xor(s2, 16, 64); s2 += __shfl_xor(s2, 32, 64);
            if (quad == 0) {
                atomicAdd(&g_stats[o], s1);
                atomicAdd(&g_stats[64 + o], s2);
            }
        }
    }
}

// ---------------- h3 = [elu(bn(h2)), pos, 0-pad] (96 ch), coef inline -------
__global__ void h3_build(const void* __restrict__ pos,
                         const void* __restrict__ gamma,
                         const void* __restrict__ beta, int N)
{
    __shared__ float cf[128];
    int t = threadIdx.x;
    const bool bf = (g_isbf16 != 0);
    if (t < 64) {
        float inv_n = 1.0f / (float)N;
        float mu = g_stats[t] * inv_n;
        float var = g_stats[64 + t] * inv_n - mu * mu;
        float A = rsqrtf(var + EPS) * loadf(gamma, t, bf);
        cf[t] = A;
        cf[64 + t] = loadf(beta, t, bf) - mu * A;
    }
    __syncthreads();
    int idx = blockIdx.x * blockDim.x + t;
    if (idx >= N * 96) return;
    int n = idx / 96, ch = idx - n * 96;
    float v;
    if (ch < 64) {
        float h = (float)g_h2[n * 64 + ch];
        v = h * cf[ch] + cf[64 + ch];
        v = v > 0.0f ? v : expm1f(v);
    } else if (ch < 67) {
        v = loadf(pos, n * 3 + (ch - 64), bf);
    } else {
        v = 0.0f;
    }
    g_h3[(size_t)n * 96 + ch] = __float2bfloat16(v);
}

// ---------------- conv3 Z-path: dense GEMM Z = h3 @ Wp3 ----------------
template <int STRIDE, int NTOT, int KPAD, int NPW>
__global__ __launch_bounds__(256) void gemm_kernel(int MT, int NTW)
{
    int gid = blockIdx.x * 256 + threadIdx.x;
    int gw = gid >> 6, lane = gid & 63;
    if (gw >= MT * NTW) return;
    int mt = gw % MT;
    int ntb = (gw / MT) * NPW;
    int m = lane & 15, quad = lane >> 4;
    const short* hrow = (const short*)g_h3 + (size_t)(mt * 16 + m) * STRIDE;
    floatx4 acc[NPW] = {};
    const int KB = KPAD / 32;
#pragma unroll
    for (int kk = 0; kk < KB; ++kk) {
        short8 a = *(const short8*)(hrow + kk * 32 + quad * 8);
#pragma unroll
        for (int i = 0; i < NPW; ++i) {
            const short* bp = (const short*)g_Wp3 +
                (((size_t)(ntb + i) * KB + kk) * 64 + lane) * 8;
            short8 b = *(const short8*)bp;
            acc[i] = __builtin_amdgcn_mfma_f32_16x16x32_bf16(a, b, acc[i], 0, 0, 0);
        }
    }
    int col = lane & 15;
    int rowbase = mt * 16 + quad * 4;
#pragma unroll
    for (int i = 0; i < NPW; ++i) {
        int ncol = (ntb + i) * 16 + col;
#pragma unroll
        for (int r = 0; r < 4; ++r)
            g_Z[(size_t)(rowbase + r) * NTOT + ncol] = __float2bfloat16(acc[i][r]);
    }
}

// ---------------- conv3: readlane gather-aggregate (COUT=32) ----------------
template <int COUT, int NTOT>
__global__ __launch_bounds__(256) void agg_kernel(const void* __restrict__ bias,
                                                  void* __restrict__ out_ext, int N)
{
    int wid = threadIdx.x >> 6, lane = threadIdx.x & 63;
    int n = blockIdx.x * 4 + wid;
    if (n >= N) return;
    const bool bf = (g_isbf16 != 0);
    const unsigned short* zp = (const unsigned short*)g_Z;
    int e0 = g_offs[n], e1 = g_offs[n + 1];
    float acc = 0.0f;
    int o = lane & 31, bh = lane >> 5;
    for (int base = e0; base < e1; base += 64) {
        int cnt = e1 - base; if (cnt > 64) cnt = 64;
        uint4 r0 = make_uint4(0, 0, 0, 0), r1 = make_uint4(0, 0, 0, 0);
        if (lane < cnt) {
            size_t le = (size_t)(base + lane) * 2;
            r0 = g_emeta[le];
            r1 = g_emeta[le + 1];
        }
        for (int j = 0; j < cnt; ++j) {
            int sn = __builtin_amdgcn_readlane((int)r0.x, j);
            unsigned int wy = (unsigned int)__builtin_amdgcn_readlane((int)r0.y, j);
            unsigned int wz = (unsigned int)__builtin_amdgcn_readlane((int)r0.z, j);
            unsigned int bw = (unsigned int)__builtin_amdgcn_readlane((int)r0.w, j);
            unsigned int bx = (unsigned int)__builtin_amdgcn_readlane((int)r1.x, j);
            unsigned int by = (unsigned int)__builtin_amdgcn_readlane((int)r1.y, j);
            unsigned int bz = (unsigned int)__builtin_amdgcn_readlane((int)r1.z, j);
            unsigned int w4  = bh ? wz : wy;
            unsigned int ba  = bh ? by : bw;
            unsigned int bbv = bh ? bz : bx;
            const unsigned short* zr = zp + (size_t)sn * NTOT;
#pragma unroll
            for (int bi = 0; bi < 4; ++bi) {
                int wxv = (int)((w4 >> (8 * bi)) & 0xFFu);
                unsigned int bbits = (((bi & 2) ? bbv : ba) >> (16 * (bi & 1))) & 0xFFFFu;
                acc += bf16f(bbits) * bf16f(zr[wxv * 32 + o]);
            }
        }
    }
    acc += __shfl_xor(acc, 32, 64);
    if (lane >= 32) return;
    int deg = e1 - e0;
    float inv = 1.0f / (float)(deg < 1 ? 1 : deg);
    float v = acc * inv + bf16f(zp[(size_t)n * NTOT + 27 * COUT + o])
            + loadf(bias, o, bf);
    if (bf) ((__hip_bfloat16*)out_ext)[n * COUT + o] = __float2bfloat16(v);
    else    ((float*)out_ext)[n * COUT + o] = v;
}

extern "C" void kernel_launch(void* const* d_in, const int* in_sizes, int n_in,
                              void* d_out, int out_size, void* d_ws, size_t ws_size,
                              hipStream_t stream)
{
    const void* x      = d_in[0];
    const int*  eindex = (const int*)d_in[1];
    const void* eattr  = d_in[2];
    const void* pos    = d_in[3];
    const void* W1     = d_in[4];
    const void* root1  = d_in[5];
    const void* b1     = d_in[6];
    const void* W2     = d_in[7];
    const void* root2  = d_in[8];
    const void* b2     = d_in[9];
    const void* gamma  = d_in[10];
    const void* beta   = d_in[11];
    const void* W3     = d_in[12];
    const void* root3  = d_in[13];
    const void* b3     = d_in[14];
    (void)d_ws; (void)ws_size; (void)n_in; (void)out_size;

    const int N = in_sizes[0] / 32;
    const int E = in_sizes[1] / 2;
    const int* srcp = eindex;
    const int* dstp = eindex + E;

    // K1: init + detect
    init_detect<<<(N + 255) / 256, 256, 0, stream>>>((const unsigned int*)x, N);
    // K2: count + cast_x + pack W1/W2/W3
    {
        int tot = E + N * 32 + 28672 + 57344 + 86016;
        misc_kernel<<<(tot + 255) / 256, 256, 0, stream>>>(
            dstp, x, W1, root1, W2, root2, W3, root3, E, N);
    }
    // K3: scan
    scan_kernel<<<1, 1024, 0, stream>>>(N, (N + 1023) / 1024);
    // K4: basis + CSR fill
    basis_fill<<<(E + 255) / 256, 256, 0, stream>>>(eattr, srcp, dstp, E);

    int nb16 = (N + 15) / 16;
    // K5: conv1 fused, g_h0 -> g_h1, ELU
    fused_conv<32, true, 0, 1><<<nb16, 1024, 0, stream>>>(b1, N);
    // K6: conv2 fused, g_h1 -> g_h2, raw + BN stats
    fused_conv<64, false, 1, 2><<<nb16, 1024, 0, stream>>>(b2, N);
    // K7: h3 build (BN coef inline)
    h3_build<<<(N * 96 + 255) / 256, 256, 0, stream>>>(pos, gamma, beta, N);
    // K8: conv3 GEMM Z = h3 @ Wp3
    {
        const int NTOT = 28 * 32, KPAD = 96, NPW = 4;
        int NTW = (NTOT / 16) / NPW;   // 14
        int waves = nb16 * NTW;
        gemm_kernel<96, NTOT, KPAD, NPW><<<(waves + 3) / 4, 256, 0, stream>>>(nb16, NTW);
    }
    // K9: conv3 gather-aggregate -> d_out
    agg_kernel<32, 28 * 32><<<(N + 3) / 4, 256, 0, stream>>>(b3, d_out, N);
}

// Round 13
// 542.944 us; speedup vs baseline: 1.1388x; 1.1388x over previous
//
#include <hip/hip_runtime.h>
#include <hip/hip_bf16.h>

// SplineCNN block.
// Edge records (32 B, CSR(dst) order): d0=src, d1=wx[0..3], d2=wx[4..7],
//   d3..d6 = basis[0..7] bf16 pairs.
// conv1/conv2: fused S-scheme, 1024 thr / 16 nodes, wave-per-node.
//   Phase 1 (round-9 proven): lane = channel c (32) x bin-half bh (2);
//   32-record batches loaded into BOTH half-waves, pre-select by bh, then
//   __shfl (ds_bpermute handles VGPR lane index; readlane waterfalls - r12).
//   Plain scalar LDS += (2-way = free). NO scale pass: phase 2 splits the
//   accumulator into accS (kk<27) and accR (kk=27) and scales accS by
//   invd[slot] in the epilogue.
//   Phase 2: MFMA GEMM, SPITCH=897 scalar A-reads (conflict-free).
// conv3: Z-scheme dense MFMA GEMM + shfl gather-aggregate.

#define EPS 1e-5f
#define MAXN 50176
#define MAXE 401408
#define SPITCH 897   // mod 32 == 1 -> phase-2 scalar A-reads 2 lanes/bank (free)

typedef __attribute__((ext_vector_type(8))) short short8;
typedef __attribute__((ext_vector_type(4))) float floatx4;

__device__ int             g_deg[MAXN];
__device__ int             g_offs[MAXN + 1];
__device__ int             g_cursor[MAXN];
__device__ uint4           g_emeta[MAXE * 2];
__device__ __align__(16) __hip_bfloat16 g_h0[MAXN * 32];
__device__ __align__(16) __hip_bfloat16 g_h1[MAXN * 32];
__device__ __align__(16) __hip_bfloat16 g_h2[MAXN * 64];
__device__ __align__(16) __hip_bfloat16 g_h3[MAXN * 96];
__device__ __align__(16) __hip_bfloat16 g_Z[(size_t)MAXN * 896];
__device__ __align__(16) __hip_bfloat16 g_Wp1[28672];
__device__ __align__(16) __hip_bfloat16 g_Wp2[57344];
__device__ __align__(16) __hip_bfloat16 g_Wp3[86016];
__device__ float           g_stats[128];
__device__ int             g_isbf16;

__device__ __forceinline__ float loadf(const void* p, int i, bool bf)
{
    return bf ? (float)((const __hip_bfloat16*)p)[i] : ((const float*)p)[i];
}
__device__ __forceinline__ float bf16f(unsigned int u)
{
    return __uint_as_float(u << 16);
}

// ---------------- K1: zero-init scratch + wire dtype detect ----------------
__global__ void init_detect(const unsigned int* __restrict__ x, int n)
{
    int i = blockIdx.x * blockDim.x + threadIdx.x;
    if (blockIdx.x == 0 && threadIdx.x < 64) {
        int lane = threadIdx.x;
        int cnt = 0;
        for (int k = lane; k < 256; k += 64) {
            unsigned int lo = x[k] & 0xFFFFu;
            int ex = (int)((lo >> 7) & 0xFFu);
            if (lo == 0u || (ex >= 96 && ex <= 140)) cnt++;
        }
#pragma unroll
        for (int o = 1; o < 64; o <<= 1) cnt += __shfl_xor(cnt, o, 64);
        if (lane == 0) g_isbf16 = (cnt >= 200) ? 1 : 0;
    }
    if (i < n) { g_deg[i] = 0; g_cursor[i] = 0; }
    if (i < 128) g_stats[i] = 0.0f;
}

// ---------------- weight pack helpers (device) ----------------
template <int COUT>
__device__ __forceinline__ void prep_ws_dev(const void* W, const void* root,
                                            __hip_bfloat16* Wp, int t, bool bf)
{
    int j = t & 7;
    int lane = (t >> 3) & 63;
    int rest = t >> 9;
    int kk = rest % 28;
    int nt = rest / 28;
    int k = kk * 32 + (lane >> 4) * 8 + j;
    int o = nt * 16 + (lane & 15);
    float v = (k < 864) ? loadf(W, k * COUT + o, bf)
                        : loadf(root, (k - 864) * COUT + o, bf);
    Wp[t] = __float2bfloat16(v);
}

__device__ __forceinline__ void prep_w3_dev(const void* W, const void* root,
                                            __hip_bfloat16* Wp, int t, bool bf)
{
    const int KB = 3;   // KPAD=96
    int j = t & 7;
    int lane = (t >> 3) & 63;
    int rest = t >> 9;
    int kk = rest % KB;
    int nt = rest / KB;
    int k = kk * 32 + (lane >> 4) * 8 + j;
    int ncol = nt * 16 + (lane & 15);
    int kw = ncol >> 5;          // /32
    int o = ncol & 31;
    float v = 0.0f;
    if (k < 67)
        v = (kw < 27) ? loadf(W, (kw * 67 + k) * 32 + o, bf)
                      : loadf(root, k * 32 + o, bf);
    Wp[t] = __float2bfloat16(v);
}

// ---------------- K2: degree count + cast x + pack all weights ----------------
__global__ void misc_kernel(const int* __restrict__ dst, const void* __restrict__ x,
                            const void* W1, const void* r1,
                            const void* W2, const void* r2,
                            const void* W3, const void* r3, int E, int N)
{
    int t = blockIdx.x * blockDim.x + threadIdx.x;
    const bool bf = (g_isbf16 != 0);
    if (t < E) { atomicAdd(&g_deg[dst[t]], 1); return; }
    t -= E;
    int nx = N * 32;
    if (t < nx) { g_h0[t] = __float2bfloat16(loadf(x, t, bf)); return; }
    t -= nx;
    if (t < 28672) { prep_ws_dev<32>(W1, r1, g_Wp1, t, bf); return; }
    t -= 28672;
    if (t < 57344) { prep_ws_dev<64>(W2, r2, g_Wp2, t, bf); return; }
    t -= 57344;
    if (t < 86016) { prep_w3_dev(W3, r3, g_Wp3, t, bf); return; }
}

// ---------------- K3: exclusive scan (single block) ----------------
__global__ void scan_kernel(int n, int chunk)
{
    __shared__ int buf[1024];
    int tid = threadIdx.x;
    int begin = tid * chunk;
    int end = begin + chunk; if (end > n) end = n;
    int s = 0;
    for (int i = begin; i < end; ++i) s += g_deg[i];
    buf[tid] = s;
    __syncthreads();
    for (int o = 1; o < 1024; o <<= 1) {
        int t = (tid >= o) ? buf[tid - o] : 0;
        __syncthreads();
        buf[tid] += t;
        __syncthreads();
    }
    int base = buf[tid] - s;
    for (int i = begin; i < end; ++i) { g_offs[i] = base; base += g_deg[i]; }
    if (tid == 1023) g_offs[n] = buf[1023];
}

// ---------------- K4: basis + CSR fill (32-B edge records) ----------------
__global__ void basis_fill(const void* __restrict__ attr,
                           const int* __restrict__ src,
                           const int* __restrict__ dst, int E)
{
    int e = blockIdx.x * blockDim.x + threadIdx.x;
    if (e >= E) return;
    const bool bf = (g_isbf16 != 0);
    float f[3];
    int lo[3];
#pragma unroll
    for (int d = 0; d < 3; ++d) {
        float a = loadf(attr, e * 3 + d, bf);
        float s = a * 3.0f;
        float l = floorf(s);
        lo[d] = (int)l;
        f[d] = s - l;
    }
    const int p3[3] = {1, 3, 9};
    unsigned int wxp0 = 0, wxp1 = 0;
    unsigned short bb[8];
#pragma unroll
    for (int b = 0; b < 8; ++b) {
        float w = 1.0f;
        int id = 0;
#pragma unroll
        for (int d = 0; d < 3; ++d) {
            int bit = (b >> d) & 1;
            w *= bit ? f[d] : (1.0f - f[d]);
            id += ((lo[d] + bit) % 3) * p3[d];
        }
        if (b < 4) wxp0 |= (unsigned int)id << (8 * b);
        else       wxp1 |= (unsigned int)id << (8 * (b - 4));
        union { __hip_bfloat16 h; unsigned short u; } cv;
        cv.h = __float2bfloat16(w);
        bb[b] = cv.u;
    }
    int d = dst[e];
    int p = atomicAdd(&g_cursor[d], 1);
    int slot = g_offs[d] + p;
    g_emeta[slot * 2] = make_uint4((unsigned int)src[e], wxp0, wxp1,
                                   (unsigned int)bb[0] | ((unsigned int)bb[1] << 16));
    g_emeta[slot * 2 + 1] = make_uint4(
        (unsigned int)bb[2] | ((unsigned int)bb[3] << 16),
        (unsigned int)bb[4] | ((unsigned int)bb[5] << 16),
        (unsigned int)bb[6] | ((unsigned int)bb[7] << 16), 0u);
}

// ---------------- fused conv (CIN=32) ----------------
// IN_SEL: 0 = g_h0, 1 = g_h1.  OUT_SEL: 1 = g_h1 (+ELU), 2 = g_h2 (raw).
template <int COUT, bool ELU, int IN_SEL, int OUT_SEL>
__global__ __launch_bounds__(1024, 8) void fused_conv(const void* __restrict__ bias,
                                                      int N)
{
    __shared__ float S[16 * SPITCH];
    __shared__ float invd[16];
    int tid = threadIdx.x, wid = tid >> 6, lane = tid & 63;
    int nbase = blockIdx.x * 16;
    const bool bf = (g_isbf16 != 0);
    const unsigned short* xptr = (IN_SEL == 0) ? (const unsigned short*)g_h0
                                               : (const unsigned short*)g_h1;
    const __hip_bfloat16* Wp = (COUT == 32) ? g_Wp1 : g_Wp2;

    // hoisted: offs + first 32-record batch (dual-half) overlaps zero-init
    int n = nbase + wid;
    int e0 = 0, e1 = 0;
    uint4 p0 = make_uint4(0, 0, 0, 0), p1 = make_uint4(0, 0, 0, 0);
    if (n < N) {
        e0 = g_offs[n]; e1 = g_offs[n + 1];
        int cnt0 = e1 - e0; if (cnt0 > 32) cnt0 = 32;
        if ((lane & 31) < cnt0) {
            size_t le = (size_t)(e0 + (lane & 31)) * 2;
            p0 = g_emeta[le];
            p1 = g_emeta[le + 1];
        }
    }

    // zero-init via b128 (16*897 = 14352 words = 3588 float4s)
    {
        float4 z4 = make_float4(0.f, 0.f, 0.f, 0.f);
        float4* S4 = (float4*)S;
        for (int i = tid; i < 3588; i += 1024) S4[i] = z4;
    }
    __syncthreads();

    // ---- phase 1: wave wid aggregates its node; lane = (channel c, bin-half bh) ----
    if (n < N) {
        float* Srow = S + wid * SPITCH;
        int c = lane & 31, bh = lane >> 5;
        float xs = bf16f(xptr[n * 32 + c]);
        if (bh == 0) Srow[864 + c] = xs;        // self-x -> root columns
        for (int base = e0; base < e1; base += 32) {
            int cnt = e1 - base; if (cnt > 32) cnt = 32;
            uint4 r0, r1;
            if (base == e0) { r0 = p0; r1 = p1; }
            else {
                r0 = make_uint4(0, 0, 0, 0); r1 = make_uint4(0, 0, 0, 0);
                if ((lane & 31) < cnt) {
                    size_t le = (size_t)(base + (lane & 31)) * 2;
                    r0 = g_emeta[le];
                    r1 = g_emeta[le + 1];
                }
            }
            // pre-select by bh; source lane sl = j+(bh<<5) has the same bh
            int selw4 = (int)(bh ? r0.z : r0.y);
            int selba = (int)(bh ? r1.y : r0.w);
            int selbb = (int)(bh ? r1.z : r1.x);
            int srcv  = (int)r0.x;
            for (int j0 = 0; j0 < cnt; j0 += 8) {
                int jn = cnt - j0; if (jn > 8) jn = 8;
                unsigned short xv[8];
#pragma unroll
                for (int j = 0; j < 8; ++j) {
                    if (j < jn) {
                        int sn = __shfl(srcv, j0 + j, 64);
                        xv[j] = xptr[(size_t)sn * 32 + c];
                    }
                }
#pragma unroll
                for (int j = 0; j < 8; ++j) {
                    if (j >= jn) break;
                    int sl = j0 + j + (bh << 5);
                    unsigned int w4  = (unsigned int)__shfl(selw4, sl, 64);
                    unsigned int ba  = (unsigned int)__shfl(selba, sl, 64);
                    unsigned int bv  = (unsigned int)__shfl(selbb, sl, 64);
                    float xf = bf16f(xv[j]);
#pragma unroll
                    for (int bi = 0; bi < 4; ++bi) {
                        int wxv = (int)((w4 >> (8 * bi)) & 0xFFu);
                        unsigned int bbits = (((bi & 2) ? bv : ba) >> (16 * (bi & 1))) & 0xFFFFu;
                        Srow[wxv * 32 + c] += bf16f(bbits) * xf;
                    }
                }
            }
        }
        int deg = e1 - e0;
        if (lane == 0) invd[wid] = 1.0f / (float)(deg < 1 ? 1 : deg);
    }
    __syncthreads();

    // ---- phase 2: wave w = col-tile w of GEMM 16 x 896 @ 896 x COUT ----
    // accS over spline k-steps (scaled by invd in epilogue), accR root step.
    if (wid * 16 < COUT) {
        int m = lane & 15, quad = lane >> 4;
        const float* Abase = S + m * SPITCH + quad * 8;
        floatx4 accS = {}, accR = {};
#pragma unroll
        for (int kk = 0; kk < 28; ++kk) {
            union { __hip_bfloat16 h[8]; short8 v; } u;
            const float* ap = Abase + kk * 32;
#pragma unroll
            for (int j = 0; j < 8; ++j) u.h[j] = __float2bfloat16(ap[j]);
            const short* bp = (const short*)Wp +
                ((size_t)(wid * 28 + kk) * 64 + lane) * 8;
            short8 b = *(const short8*)bp;
            if (kk < 27) accS = __builtin_amdgcn_mfma_f32_16x16x32_bf16(u.v, b, accS, 0, 0, 0);
            else         accR = __builtin_amdgcn_mfma_f32_16x16x32_bf16(u.v, b, accR, 0, 0, 0);
        }
        int o = wid * 16 + (lane & 15);
        float bval = loadf(bias, o, bf);
#pragma unroll
        for (int r = 0; r < 4; ++r) {
            int slot = quad * 4 + r;
            int nn = nbase + slot;
            if (nn >= N) continue;
            float v = accS[r] * invd[slot] + accR[r] + bval;
            if (ELU) v = v > 0.0f ? v : expm1f(v);
            if (OUT_SEL == 1) g_h1[nn * 32 + o] = __float2bfloat16(v);
            else              g_h2[nn * 64 + o] = __float2bfloat16(v);
        }
    }
}

// ---------------- BN stats (reads g_h2) ----------------
__global__ void bn_reduce(int n)
{
    int tid = threadIdx.x;
    int c = tid & 63;
    int r = tid >> 6;
    float s = 0.0f, s2 = 0.0f;
    for (int i = blockIdx.x * 4 + r; i < n; i += gridDim.x * 4) {
        float v = (float)g_h2[i * 64 + c];
        s += v; s2 += v * v;
    }
    __shared__ float b1s[256], b2s[256];
    b1s[tid] = s; b2s[tid] = s2;
    __syncthreads();
    if (r == 0) {
        s  = b1s[c] + b1s[c + 64] + b1s[c + 128] + b1s[c + 192];
        s2 = b2s[c] + b2s[c + 64] + b2s[c + 128] + b2s[c + 192];
        atomicAdd(&g_stats[c], s);
        atomicAdd(&g_stats[64 + c], s2);
    }
}

// ---------------- h3 = [elu(bn(h2)), pos, 0-pad] (96 ch), coef inline -------
__global__ void h3_build(const void* __restrict__ pos,
                         const void* __restrict__ gamma,
                         const void* __restrict__ beta, int N)
{
    __shared__ float cf[128];
    int t = threadIdx.x;
    const bool bf = (g_isbf16 != 0);
    if (t < 64) {
        float inv_n = 1.0f / (float)N;
        float mu = g_stats[t] * inv_n;
        float var = g_stats[64 + t] * inv_n - mu * mu;
        float A = rsqrtf(var + EPS) * loadf(gamma, t, bf);
        cf[t] = A;
        cf[64 + t] = loadf(beta, t, bf) - mu * A;
    }
    __syncthreads();
    int idx = blockIdx.x * blockDim.x + t;
    if (idx >= N * 96) return;
    int n = idx / 96, ch = idx - n * 96;
    float v;
    if (ch < 64) {
        float h = (float)g_h2[n * 64 + ch];
        v = h * cf[ch] + cf[64 + ch];
        v = v > 0.0f ? v : expm1f(v);
    } else if (ch < 67) {
        v = loadf(pos, n * 3 + (ch - 64), bf);
    } else {
        v = 0.0f;
    }
    g_h3[(size_t)n * 96 + ch] = __float2bfloat16(v);
}

// ---------------- conv3 Z-path: dense GEMM Z = h3 @ Wp3 ----------------
template <int STRIDE, int NTOT, int KPAD, int NPW>
__global__ __launch_bounds__(256) void gemm_kernel(int MT, int NTW)
{
    int gid = blockIdx.x * 256 + threadIdx.x;
    int gw = gid >> 6, lane = gid & 63;
    if (gw >= MT * NTW) return;
    int mt = gw % MT;
    int ntb = (gw / MT) * NPW;
    int m = lane & 15, quad = lane >> 4;
    const short* hrow = (const short*)g_h3 + (size_t)(mt * 16 + m) * STRIDE;
    floatx4 acc[NPW] = {};
    const int KB = KPAD / 32;
#pragma unroll
    for (int kk = 0; kk < KB; ++kk) {
        short8 a = *(const short8*)(hrow + kk * 32 + quad * 8);
#pragma unroll
        for (int i = 0; i < NPW; ++i) {
            const short* bp = (const short*)g_Wp3 +
                (((size_t)(ntb + i) * KB + kk) * 64 + lane) * 8;
            short8 b = *(const short8*)bp;
            acc[i] = __builtin_amdgcn_mfma_f32_16x16x32_bf16(a, b, acc[i], 0, 0, 0);
        }
    }
    int col = lane & 15;
    int rowbase = mt * 16 + quad * 4;
#pragma unroll
    for (int i = 0; i < NPW; ++i) {
        int ncol = (ntb + i) * 16 + col;
#pragma unroll
        for (int r = 0; r < 4; ++r)
            g_Z[(size_t)(rowbase + r) * NTOT + ncol] = __float2bfloat16(acc[i][r]);
    }
}

// ---------------- conv3: shfl gather-aggregate (COUT=32) ----------------
template <int COUT, int NTOT>
__global__ __launch_bounds__(256) void agg_kernel(const void* __restrict__ bias,
                                                  void* __restrict__ out_ext, int N)
{
    int wid = threadIdx.x >> 6, lane = threadIdx.x & 63;
    int n = blockIdx.x * 4 + wid;
    if (n >= N) return;
    const bool bf = (g_isbf16 != 0);
    const unsigned short* zp = (const unsigned short*)g_Z;
    int e0 = g_offs[n], e1 = g_offs[n + 1];
    float acc = 0.0f;
    int o = lane & 31, bh = lane >> 5;
    for (int base = e0; base < e1; base += 32) {
        int cnt = e1 - base; if (cnt > 32) cnt = 32;
        uint4 r0 = make_uint4(0, 0, 0, 0), r1 = make_uint4(0, 0, 0, 0);
        if ((lane & 31) < cnt) {
            size_t le = (size_t)(base + (lane & 31)) * 2;
            r0 = g_emeta[le];
            r1 = g_emeta[le + 1];
        }
        int selw4 = (int)(bh ? r0.z : r0.y);
        int selba = (int)(bh ? r1.y : r0.w);
        int selbb = (int)(bh ? r1.z : r1.x);
        int srcv  = (int)r0.x;
#pragma unroll 2
        for (int j = 0; j < cnt; ++j) {
            int sl = j + (bh << 5);
            int sn = __shfl(srcv, j, 64);
            unsigned int w4  = (unsigned int)__shfl(selw4, sl, 64);
            unsigned int ba  = (unsigned int)__shfl(selba, sl, 64);
            unsigned int bbv = (unsigned int)__shfl(selbb, sl, 64);
            const unsigned short* zr = zp + (size_t)sn * NTOT;
#pragma unroll
            for (int bi = 0; bi < 4; ++bi) {
                int wxv = (int)((w4 >> (8 * bi)) & 0xFFu);
                unsigned int bbits = (((bi & 2) ? bbv : ba) >> (16 * (bi & 1))) & 0xFFFFu;
                acc += bf16f(bbits) * bf16f(zr[wxv * 32 + o]);
            }
        }
    }
    acc += __shfl_xor(acc, 32, 64);
    if (lane >= 32) return;
    int deg = e1 - e0;
    float inv = 1.0f / (float)(deg < 1 ? 1 : deg);
    float v = acc * inv + bf16f(zp[(size_t)n * NTOT + 27 * COUT + o])
            + loadf(bias, o, bf);
    if (bf) ((__hip_bfloat16*)out_ext)[n * COUT + o] = __float2bfloat16(v);
    else    ((float*)out_ext)[n * COUT + o] = v;
}

extern "C" void kernel_launch(void* const* d_in, const int* in_sizes, int n_in,
                              void* d_out, int out_size, void* d_ws, size_t ws_size,
                              hipStream_t stream)
{
    const void* x      = d_in[0];
    const int*  eindex = (const int*)d_in[1];
    const void* eattr  = d_in[2];
    const void* pos    = d_in[3];
    const void* W1     = d_in[4];
    const void* root1  = d_in[5];
    const void* b1     = d_in[6];
    const void* W2     = d_in[7];
    const void* root2  = d_in[8];
    const void* b2     = d_in[9];
    const void* gamma  = d_in[10];
    const void* beta   = d_in[11];
    const void* W3     = d_in[12];
    const void* root3  = d_in[13];
    const void* b3     = d_in[14];
    (void)d_ws; (void)ws_size; (void)n_in; (void)out_size;

    const int N = in_sizes[0] / 32;
    const int E = in_sizes[1] / 2;
    const int* srcp = eindex;
    const int* dstp = eindex + E;

    // K1: init + detect
    init_detect<<<(N + 255) / 256, 256, 0, stream>>>((const unsigned int*)x, N);
    // K2: count + cast_x + pack W1/W2/W3
    {
        int tot = E + N * 32 + 28672 + 57344 + 86016;
        misc_kernel<<<(tot + 255) / 256, 256, 0, stream>>>(
            dstp, x, W1, root1, W2, root2, W3, root3, E, N);
    }
    // K3: scan
    scan_kernel<<<1, 1024, 0, stream>>>(N, (N + 1023) / 1024);
    // K4: basis + CSR fill
    basis_fill<<<(E + 255) / 256, 256, 0, stream>>>(eattr, srcp, dstp, E);

    int nb16 = (N + 15) / 16;
    // K5: conv1 fused, g_h0 -> g_h1, ELU
    fused_conv<32, true, 0, 1><<<nb16, 1024, 0, stream>>>(b1, N);
    // K6: conv2 fused, g_h1 -> g_h2, raw
    fused_conv<64, false, 1, 2><<<nb16, 1024, 0, stream>>>(b2, N);
    // K6b: BN stats
    bn_reduce<<<120, 256, 0, stream>>>(N);
    // K7: h3 build (BN coef inline)
    h3_build<<<(N * 96 + 255) / 256, 256, 0, stream>>>(pos, gamma, beta, N);
    // K8: conv3 GEMM Z = h3 @ Wp3
    {
        const int NTOT = 28 * 32, KPAD = 96, NPW = 4;
        int NTW = (NTOT / 16) / NPW;   // 14
        int waves = nb16 * NTW;
        gemm_kernel<96, NTOT, KPAD, NPW><<<(waves + 3) / 4, 256, 0, stream>>>(nb16, NTW);
    }
    // K9: conv3 gather-aggregate -> d_out
    agg_kernel<32, 28 * 32><<<(N + 3) / 4, 256, 0, stream>>>(b3, d_out, N);
}

// Round 14
// 500.232 us; speedup vs baseline: 1.2361x; 1.0854x over previous
//
#include <hip/hip_runtime.h>
#include <hip/hip_bf16.h>

// SplineCNN block.
// Edge records (32 B, CSR(dst) order), word order:
//   w0=wx[0..3], w1=wx[4..7], w2=bas01, w3=bas23, w4=bas45, w5=bas67, w6=src, w7=0
// conv1/conv2 fused, 512 thr / 8 nodes, wave-per-node:
//   Phase 1 = MFMA scatter-GEMM: S^T(32ch x 27bin) = X^T(32xK) @ P(Kx27),
//   K = deg padded to 32. P built in registers (bin vs wx byte match selects
//   bf16 bas bits); records staged per-node in LDS (2 b128 writes, b128/b64/b32
//   reads); A-fragments gathered straight from x. S stored bf16 (pitch 904).
//   Phase 2: MFMA GEMM 16x896 @ 896xCOUT with A = 28 ds_read_b128 (no cvt),
//   accS/accR split, invd scaling in epilogue.
// conv3: Z-scheme dense MFMA GEMM + shfl gather-aggregate (r13-proven).

#define EPS 1e-5f
#define MAXN 50176
#define MAXE 401408
#define SP2 904   // bf16 elems per S row: 864 spline + 32 root + 8 pad

typedef __attribute__((ext_vector_type(8))) short short8;
typedef __attribute__((ext_vector_type(4))) float floatx4;

__device__ int             g_deg[MAXN];
__device__ int             g_offs[MAXN + 1];
__device__ int             g_cursor[MAXN];
__device__ uint4           g_emeta[MAXE * 2];
__device__ __align__(16) __hip_bfloat16 g_h0[MAXN * 32];
__device__ __align__(16) __hip_bfloat16 g_h1[MAXN * 32];
__device__ __align__(16) __hip_bfloat16 g_h2[MAXN * 64];
__device__ __align__(16) __hip_bfloat16 g_h3[MAXN * 96];
__device__ __align__(16) __hip_bfloat16 g_Z[(size_t)MAXN * 896];
__device__ __align__(16) __hip_bfloat16 g_Wp1[28672];
__device__ __align__(16) __hip_bfloat16 g_Wp2[57344];
__device__ __align__(16) __hip_bfloat16 g_Wp3[86016];
__device__ float           g_stats[128];
__device__ int             g_isbf16;

__device__ __forceinline__ float loadf(const void* p, int i, bool bf)
{
    return bf ? (float)((const __hip_bfloat16*)p)[i] : ((const float*)p)[i];
}
__device__ __forceinline__ float bf16f(unsigned int u)
{
    return __uint_as_float(u << 16);
}
__device__ __forceinline__ unsigned short bfbits(float f)
{
    union { __hip_bfloat16 h; unsigned short u; } cv;
    cv.h = __float2bfloat16(f);
    return cv.u;
}

// ---------------- K1: zero-init scratch + wire dtype detect ----------------
__global__ void init_detect(const unsigned int* __restrict__ x, int n)
{
    int i = blockIdx.x * blockDim.x + threadIdx.x;
    if (blockIdx.x == 0 && threadIdx.x < 64) {
        int lane = threadIdx.x;
        int cnt = 0;
        for (int k = lane; k < 256; k += 64) {
            unsigned int lo = x[k] & 0xFFFFu;
            int ex = (int)((lo >> 7) & 0xFFu);
            if (lo == 0u || (ex >= 96 && ex <= 140)) cnt++;
        }
#pragma unroll
        for (int o = 1; o < 64; o <<= 1) cnt += __shfl_xor(cnt, o, 64);
        if (lane == 0) g_isbf16 = (cnt >= 200) ? 1 : 0;
    }
    if (i < n) { g_deg[i] = 0; g_cursor[i] = 0; }
    if (i < 128) g_stats[i] = 0.0f;
}

// ---------------- weight pack helpers (device) ----------------
template <int COUT>
__device__ __forceinline__ void prep_ws_dev(const void* W, const void* root,
                                            __hip_bfloat16* Wp, int t, bool bf)
{
    int j = t & 7;
    int lane = (t >> 3) & 63;
    int rest = t >> 9;
    int kk = rest % 28;
    int nt = rest / 28;
    int k = kk * 32 + (lane >> 4) * 8 + j;
    int o = nt * 16 + (lane & 15);
    float v = (k < 864) ? loadf(W, k * COUT + o, bf)
                        : loadf(root, (k - 864) * COUT + o, bf);
    Wp[t] = __float2bfloat16(v);
}

__device__ __forceinline__ void prep_w3_dev(const void* W, const void* root,
                                            __hip_bfloat16* Wp, int t, bool bf)
{
    const int KB = 3;   // KPAD=96
    int j = t & 7;
    int lane = (t >> 3) & 63;
    int rest = t >> 9;
    int kk = rest % KB;
    int nt = rest / KB;
    int k = kk * 32 + (lane >> 4) * 8 + j;
    int ncol = nt * 16 + (lane & 15);
    int kw = ncol >> 5;
    int o = ncol & 31;
    float v = 0.0f;
    if (k < 67)
        v = (kw < 27) ? loadf(W, (kw * 67 + k) * 32 + o, bf)
                      : loadf(root, k * 32 + o, bf);
    Wp[t] = __float2bfloat16(v);
}

// ---------------- K2: degree count + cast x + pack all weights ----------------
__global__ void misc_kernel(const int* __restrict__ dst, const void* __restrict__ x,
                            const void* W1, const void* r1,
                            const void* W2, const void* r2,
                            const void* W3, const void* r3, int E, int N)
{
    int t = blockIdx.x * blockDim.x + threadIdx.x;
    const bool bf = (g_isbf16 != 0);
    if (t < E) { atomicAdd(&g_deg[dst[t]], 1); return; }
    t -= E;
    int nx = N * 32;
    if (t < nx) { g_h0[t] = __float2bfloat16(loadf(x, t, bf)); return; }
    t -= nx;
    if (t < 28672) { prep_ws_dev<32>(W1, r1, g_Wp1, t, bf); return; }
    t -= 28672;
    if (t < 57344) { prep_ws_dev<64>(W2, r2, g_Wp2, t, bf); return; }
    t -= 57344;
    if (t < 86016) { prep_w3_dev(W3, r3, g_Wp3, t, bf); return; }
}

// ---------------- K3: exclusive scan (single block) ----------------
__global__ void scan_kernel(int n, int chunk)
{
    __shared__ int buf[1024];
    int tid = threadIdx.x;
    int begin = tid * chunk;
    int end = begin + chunk; if (end > n) end = n;
    int s = 0;
    for (int i = begin; i < end; ++i) s += g_deg[i];
    buf[tid] = s;
    __syncthreads();
    for (int o = 1; o < 1024; o <<= 1) {
        int t = (tid >= o) ? buf[tid - o] : 0;
        __syncthreads();
        buf[tid] += t;
        __syncthreads();
    }
    int base = buf[tid] - s;
    for (int i = begin; i < end; ++i) { g_offs[i] = base; base += g_deg[i]; }
    if (tid == 1023) g_offs[n] = buf[1023];
}

// ---------------- K4: basis + CSR fill (32-B edge records) ----------------
__global__ void basis_fill(const void* __restrict__ attr,
                           const int* __restrict__ src,
                           const int* __restrict__ dst, int E)
{
    int e = blockIdx.x * blockDim.x + threadIdx.x;
    if (e >= E) return;
    const bool bf = (g_isbf16 != 0);
    float f[3];
    int lo[3];
#pragma unroll
    for (int d = 0; d < 3; ++d) {
        float a = loadf(attr, e * 3 + d, bf);
        float s = a * 3.0f;
        float l = floorf(s);
        lo[d] = (int)l;
        f[d] = s - l;
    }
    const int p3[3] = {1, 3, 9};
    unsigned int wxp0 = 0, wxp1 = 0;
    unsigned short bb[8];
#pragma unroll
    for (int b = 0; b < 8; ++b) {
        float w = 1.0f;
        int id = 0;
#pragma unroll
        for (int d = 0; d < 3; ++d) {
            int bit = (b >> d) & 1;
            w *= bit ? f[d] : (1.0f - f[d]);
            id += ((lo[d] + bit) % 3) * p3[d];
        }
        if (b < 4) wxp0 |= (unsigned int)id << (8 * b);
        else       wxp1 |= (unsigned int)id << (8 * (b - 4));
        bb[b] = bfbits(w);
    }
    int d = dst[e];
    int p = atomicAdd(&g_cursor[d], 1);
    int slot = g_offs[d] + p;
    g_emeta[slot * 2] = make_uint4(wxp0, wxp1,
                                   (unsigned int)bb[0] | ((unsigned int)bb[1] << 16),
                                   (unsigned int)bb[2] | ((unsigned int)bb[3] << 16));
    g_emeta[slot * 2 + 1] = make_uint4(
        (unsigned int)bb[4] | ((unsigned int)bb[5] << 16),
        (unsigned int)bb[6] | ((unsigned int)bb[7] << 16),
        (unsigned int)src[e], 0u);
}

// ---------------- fused conv (CIN=32), 8 nodes / 512 thr ----------------
// IN_SEL: 0 = g_h0, 1 = g_h1.  OUT_SEL: 1 = g_h1 (+ELU), 2 = g_h2 (raw).
template <int COUT, bool ELU, int IN_SEL, int OUT_SEL>
__global__ __launch_bounds__(512, 8) void fused_conv(const void* __restrict__ bias,
                                                     int N)
{
    __shared__ unsigned short Sb[8 * SP2];
    __shared__ uint4 recs[8][64];
    __shared__ float invd[8];
    int tid = threadIdx.x, wid = tid >> 6, lane = tid & 63;
    int nbase = blockIdx.x * 8;
    const bool bf = (g_isbf16 != 0);
    const unsigned short* xptr = (IN_SEL == 0) ? (const unsigned short*)g_h0
                                               : (const unsigned short*)g_h1;
    const __hip_bfloat16* Wp = (COUT == 32) ? g_Wp1 : g_Wp2;

    int n = nbase + wid;
    int m = lane & 15, quad = lane >> 4;

    // ---- phase 1: wave wid builds S row for its node via MFMA scatter-GEMM ----
    if (n < N) {
        int e0 = g_offs[n], e1 = g_offs[n + 1];
        floatx4 C00 = {}, C01 = {}, C10 = {}, C11 = {};
        uint4* myrec = &recs[wid][0];
        int bin0 = m, bin1 = m + 16;
        for (int base = e0; base < e1; base += 32) {
            int cnt = e1 - base; if (cnt > 32) cnt = 32;
            if (lane < 32) {
                uint4 v0 = make_uint4(0, 0, 0, 0), v1 = make_uint4(0, 0, 0, 0);
                if (lane < cnt) {
                    size_t le = (size_t)(base + lane) * 2;
                    v0 = g_emeta[le];
                    v1 = g_emeta[le + 1];
                }
                myrec[2 * lane] = v0;
                myrec[2 * lane + 1] = v1;
            }
            // same-wave DS ordering: no barrier needed (wave-private region)
            unsigned a0w[4] = {0, 0, 0, 0}, a1w[4] = {0, 0, 0, 0};
            unsigned b0w[4] = {0, 0, 0, 0}, b1w[4] = {0, 0, 0, 0};
#pragma unroll
            for (int j = 0; j < 8; ++j) {
                int kidx = quad * 8 + j;
                uint4 ra = myrec[2 * kidx];                       // wx03,wx47,bas01,bas23
                uint2 rb = *(const uint2*)&myrec[2 * kidx + 1];   // bas45,bas67
                int sn = (int)((const unsigned*)&myrec[2 * kidx + 1])[2];
                unsigned av0 = xptr[(size_t)sn * 32 + m];
                unsigned av1 = xptr[(size_t)sn * 32 + 16 + m];
                unsigned p0 = 0, p1 = 0;
#pragma unroll
                for (int b = 0; b < 8; ++b) {
                    unsigned wx = ((b < 4 ? ra.x : ra.y) >> (8 * (b & 3))) & 0xFFu;
                    unsigned basw = (b < 2) ? ra.z : (b < 4) ? ra.w
                                  : (b < 6) ? rb.x : rb.y;
                    unsigned bas = (b & 1) ? (basw >> 16) : (basw & 0xFFFFu);
                    if (wx == (unsigned)bin0) p0 = bas;
                    if (wx == (unsigned)bin1) p1 = bas;
                }
                unsigned sh = 16 * (j & 1);
                a0w[j >> 1] |= av0 << sh;
                a1w[j >> 1] |= av1 << sh;
                b0w[j >> 1] |= p0 << sh;
                b1w[j >> 1] |= p1 << sh;
            }
            union U { unsigned w[4]; short8 v; } A0, A1, B0, B1;
#pragma unroll
            for (int q = 0; q < 4; ++q) {
                A0.w[q] = a0w[q]; A1.w[q] = a1w[q];
                B0.w[q] = b0w[q]; B1.w[q] = b1w[q];
            }
            C00 = __builtin_amdgcn_mfma_f32_16x16x32_bf16(A0.v, B0.v, C00, 0, 0, 0);
            C01 = __builtin_amdgcn_mfma_f32_16x16x32_bf16(A0.v, B1.v, C01, 0, 0, 0);
            C10 = __builtin_amdgcn_mfma_f32_16x16x32_bf16(A1.v, B0.v, C10, 0, 0, 0);
            C11 = __builtin_amdgcn_mfma_f32_16x16x32_bf16(A1.v, B1.v, C11, 0, 0, 0);
        }
        // writeback: C[mt][nt] lane holds col=m (bin-in-tile), rows quad*4+r (ch)
        unsigned short* Srow = Sb + wid * SP2;
        {
            floatx4 Cf[4] = {C00, C01, C10, C11};
#pragma unroll
            for (int f = 0; f < 4; ++f) {
                int mt = f >> 1, nt = f & 1;
                int bin = nt * 16 + m;
                if (bin < 27) {
                    union { unsigned short h[4]; uint2 u; } pk;
#pragma unroll
                    for (int r = 0; r < 4; ++r) pk.h[r] = bfbits(Cf[f][r]);
                    *(uint2*)(Srow + bin * 32 + mt * 16 + quad * 4) = pk.u;
                }
            }
        }
        if (lane < 32) Srow[864 + lane] = xptr[(size_t)n * 32 + lane];
        if (lane == 0) {
            int deg = e1 - e0;
            invd[wid] = 1.0f / (float)(deg < 1 ? 1 : deg);
        }
    }
    __syncthreads();

    // ---- phase 2: wave w = col-tile w of GEMM 16 x 896 @ 896 x COUT ----
    if (wid * 16 < COUT) {
        int mrow = m & 7;   // 8 nodes; rows 8..15 duplicate (discarded below)
        const unsigned short* Ab = Sb + mrow * SP2 + quad * 8;
        floatx4 accS = {}, accR = {};
#pragma unroll
        for (int kk = 0; kk < 28; ++kk) {
            short8 a = *(const short8*)(Ab + kk * 32);
            const short* bp = (const short*)Wp +
                ((size_t)(wid * 28 + kk) * 64 + lane) * 8;
            short8 b = *(const short8*)bp;
            if (kk < 27) accS = __builtin_amdgcn_mfma_f32_16x16x32_bf16(a, b, accS, 0, 0, 0);
            else         accR = __builtin_amdgcn_mfma_f32_16x16x32_bf16(a, b, accR, 0, 0, 0);
        }
        int o = wid * 16 + m;
        float bval = loadf(bias, o, bf);
#pragma unroll
        for (int r = 0; r < 4; ++r) {
            int slot = quad * 4 + r;
            if (slot >= 8) continue;
            int nn = nbase + slot;
            if (nn >= N) continue;
            float v = accS[r] * invd[slot] + accR[r] + bval;
            if (ELU) v = v > 0.0f ? v : expm1f(v);
            if (OUT_SEL == 1) g_h1[nn * 32 + o] = __float2bfloat16(v);
            else              g_h2[nn * 64 + o] = __float2bfloat16(v);
        }
    }
}

// ---------------- BN stats (reads g_h2) ----------------
__global__ void bn_reduce(int n)
{
    int tid = threadIdx.x;
    int c = tid & 63;
    int r = tid >> 6;
    float s = 0.0f, s2 = 0.0f;
    for (int i = blockIdx.x * 4 + r; i < n; i += gridDim.x * 4) {
        float v = (float)g_h2[i * 64 + c];
        s += v; s2 += v * v;
    }
    __shared__ float b1s[256], b2s[256];
    b1s[tid] = s; b2s[tid] = s2;
    __syncthreads();
    if (r == 0) {
        s  = b1s[c] + b1s[c + 64] + b1s[c + 128] + b1s[c + 192];
        s2 = b2s[c] + b2s[c + 64] + b2s[c + 128] + b2s[c + 192];
        atomicAdd(&g_stats[c], s);
        atomicAdd(&g_stats[64 + c], s2);
    }
}

// ---------------- h3 = [elu(bn(h2)), pos, 0-pad] (96 ch), coef inline -------
__global__ void h3_build(const void* __restrict__ pos,
                         const void* __restrict__ gamma,
                         const void* __restrict__ beta, int N)
{
    __shared__ float cf[128];
    int t = threadIdx.x;
    const bool bf = (g_isbf16 != 0);
    if (t < 64) {
        float inv_n = 1.0f / (float)N;
        float mu = g_stats[t] * inv_n;
        float var = g_stats[64 + t] * inv_n - mu * mu;
        float A = rsqrtf(var + EPS) * loadf(gamma, t, bf);
        cf[t] = A;
        cf[64 + t] = loadf(beta, t, bf) - mu * A;
    }
    __syncthreads();
    int idx = blockIdx.x * blockDim.x + t;
    if (idx >= N * 96) return;
    int n = idx / 96, ch = idx - n * 96;
    float v;
    if (ch < 64) {
        float h = (float)g_h2[n * 64 + ch];
        v = h * cf[ch] + cf[64 + ch];
        v = v > 0.0f ? v : expm1f(v);
    } else if (ch < 67) {
        v = loadf(pos, n * 3 + (ch - 64), bf);
    } else {
        v = 0.0f;
    }
    g_h3[(size_t)n * 96 + ch] = __float2bfloat16(v);
}

// ---------------- conv3 Z-path: dense GEMM Z = h3 @ Wp3 ----------------
template <int STRIDE, int NTOT, int KPAD, int NPW>
__global__ __launch_bounds__(256) void gemm_kernel(int MT, int NTW)
{
    int gid = blockIdx.x * 256 + threadIdx.x;
    int gw = gid >> 6, lane = gid & 63;
    if (gw >= MT * NTW) return;
    int mt = gw % MT;
    int ntb = (gw / MT) * NPW;
    int m = lane & 15, quad = lane >> 4;
    const short* hrow = (const short*)g_h3 + (size_t)(mt * 16 + m) * STRIDE;
    floatx4 acc[NPW] = {};
    const int KB = KPAD / 32;
#pragma unroll
    for (int kk = 0; kk < KB; ++kk) {
        short8 a = *(const short8*)(hrow + kk * 32 + quad * 8);
#pragma unroll
        for (int i = 0; i < NPW; ++i) {
            const short* bp = (const short*)g_Wp3 +
                (((size_t)(ntb + i) * KB + kk) * 64 + lane) * 8;
            short8 b = *(const short8*)bp;
            acc[i] = __builtin_amdgcn_mfma_f32_16x16x32_bf16(a, b, acc[i], 0, 0, 0);
        }
    }
    int col = lane & 15;
    int rowbase = mt * 16 + quad * 4;
#pragma unroll
    for (int i = 0; i < NPW; ++i) {
        int ncol = (ntb + i) * 16 + col;
#pragma unroll
        for (int r = 0; r < 4; ++r)
            g_Z[(size_t)(rowbase + r) * NTOT + ncol] = __float2bfloat16(acc[i][r]);
    }
}

// ---------------- conv3: shfl gather-aggregate (COUT=32) ----------------
template <int COUT, int NTOT>
__global__ __launch_bounds__(256) void agg_kernel(const void* __restrict__ bias,
                                                  void* __restrict__ out_ext, int N)
{
    int wid = threadIdx.x >> 6, lane = threadIdx.x & 63;
    int n = blockIdx.x * 4 + wid;
    if (n >= N) return;
    const bool bf = (g_isbf16 != 0);
    const unsigned short* zp = (const unsigned short*)g_Z;
    int e0 = g_offs[n], e1 = g_offs[n + 1];
    float acc = 0.0f;
    int o = lane & 31, bh = lane >> 5;
    for (int base = e0; base < e1; base += 32) {
        int cnt = e1 - base; if (cnt > 32) cnt = 32;
        uint4 r0 = make_uint4(0, 0, 0, 0), r1 = make_uint4(0, 0, 0, 0);
        if ((lane & 31) < cnt) {
            size_t le = (size_t)(base + (lane & 31)) * 2;
            r0 = g_emeta[le];
            r1 = g_emeta[le + 1];
        }
        // layout: r0 = wx03,wx47,bas01,bas23 ; r1 = bas45,bas67,src,0
        int selw4 = (int)(bh ? r0.y : r0.x);
        int selba = (int)(bh ? r1.x : r0.z);
        int selbb = (int)(bh ? r1.y : r0.w);
        int srcv  = (int)r1.z;
#pragma unroll 2
        for (int j = 0; j < cnt; ++j) {
            int sl = j + (bh << 5);
            int sn = __shfl(srcv, j, 64);
            unsigned int w4  = (unsigned int)__shfl(selw4, sl, 64);
            unsigned int ba  = (unsigned int)__shfl(selba, sl, 64);
            unsigned int bbv = (unsigned int)__shfl(selbb, sl, 64);
            const unsigned short* zr = zp + (size_t)sn * NTOT;
#pragma unroll
            for (int bi = 0; bi < 4; ++bi) {
                int wxv = (int)((w4 >> (8 * bi)) & 0xFFu);
                unsigned int bbits = (((bi & 2) ? bbv : ba) >> (16 * (bi & 1))) & 0xFFFFu;
                acc += bf16f(bbits) * bf16f(zr[wxv * 32 + o]);
            }
        }
    }
    acc += __shfl_xor(acc, 32, 64);
    if (lane >= 32) return;
    int deg = e1 - e0;
    float inv = 1.0f / (float)(deg < 1 ? 1 : deg);
    float v = acc * inv + bf16f(zp[(size_t)n * NTOT + 27 * COUT + o])
            + loadf(bias, o, bf);
    if (bf) ((__hip_bfloat16*)out_ext)[n * COUT + o] = __float2bfloat16(v);
    else    ((float*)out_ext)[n * COUT + o] = v;
}

extern "C" void kernel_launch(void* const* d_in, const int* in_sizes, int n_in,
                              void* d_out, int out_size, void* d_ws, size_t ws_size,
                              hipStream_t stream)
{
    const void* x      = d_in[0];
    const int*  eindex = (const int*)d_in[1];
    const void* eattr  = d_in[2];
    const void* pos    = d_in[3];
    const void* W1     = d_in[4];
    const void* root1  = d_in[5];
    const void* b1     = d_in[6];
    const void* W2     = d_in[7];
    const void* root2  = d_in[8];
    const void* b2     = d_in[9];
    const void* gamma  = d_in[10];
    const void* beta   = d_in[11];
    const void* W3     = d_in[12];
    const void* root3  = d_in[13];
    const void* b3     = d_in[14];
    (void)d_ws; (void)ws_size; (void)n_in; (void)out_size;

    const int N = in_sizes[0] / 32;
    const int E = in_sizes[1] / 2;
    const int* srcp = eindex;
    const int* dstp = eindex + E;

    init_detect<<<(N + 255) / 256, 256, 0, stream>>>((const unsigned int*)x, N);
    {
        int tot = E + N * 32 + 28672 + 57344 + 86016;
        misc_kernel<<<(tot + 255) / 256, 256, 0, stream>>>(
            dstp, x, W1, root1, W2, root2, W3, root3, E, N);
    }
    scan_kernel<<<1, 1024, 0, stream>>>(N, (N + 1023) / 1024);
    basis_fill<<<(E + 255) / 256, 256, 0, stream>>>(eattr, srcp, dstp, E);

    int nb8 = (N + 7) / 8;
    fused_conv<32, true, 0, 1><<<nb8, 512, 0, stream>>>(b1, N);
    fused_conv<64, false, 1, 2><<<nb8, 512, 0, stream>>>(b2, N);
    bn_reduce<<<120, 256, 0, stream>>>(N);
    h3_build<<<(N * 96 + 255) / 256, 256, 0, stream>>>(pos, gamma, beta, N);
    {
        const int NTOT = 28 * 32, KPAD = 96, NPW = 4;
        int NTW = (NTOT / 16) / NPW;   // 14
        int MT = (N + 15) / 16;
        int waves = MT * NTW;
        gemm_kernel<96, NTOT, KPAD, NPW><<<(waves + 3) / 4, 256, 0, stream>>>(MT, NTW);
    }
    agg_kernel<32, 28 * 32><<<(N + 3) / 4, 256, 0, stream>>>(b3, d_out, N);
}

// Round 16
// 433.125 us; speedup vs baseline: 1.4276x; 1.1549x over previous
//
#include <hip/hip_runtime.h>
#include <hip/hip_bf16.h>

// SplineCNN block.
// Edge records (32 B, CSR(dst) order), word order:
//   w0=wx[0..3], w1=wx[4..7], w2=bas01, w3=bas23, w4=bas45, w5=bas67, w6=src, w7=0
// conv1/conv2 fused, 512 thr / 8 nodes, wave-per-node:
//   Phase 1 = MFMA scatter-GEMM: S^T(32ch x 27bin) = X^T(32xK) @ P(Kx27),
//   P built in registers (bin vs wx byte match); records staged per-node in LDS
//   with an explicit s_waitcnt(0) between staging writes and read-back
//   (intra-wave DS ordering is NOT assumed -- r15 flaked without it).
//   S stored bf16 (pitch 904). Phase 2: MFMA GEMM, A = 28 ds_read_b128,
//   accS/accR split, invd scaling in epilogue.
// conv3: Z-scheme dense MFMA GEMM + shfl gather-aggregate.
// Scan: two-level parallel (196-block partial + top + add).

#define EPS 1e-5f
#define MAXN 50176
#define MAXE 401408
#define SP2 904   // bf16 elems per S row: 864 spline + 32 root + 8 pad

typedef __attribute__((ext_vector_type(8))) short short8;
typedef __attribute__((ext_vector_type(4))) float floatx4;

__device__ int             g_deg[MAXN];
__device__ int             g_offs[MAXN + 1];
__device__ int             g_cursor[MAXN];
__device__ int             g_bsum[256];
__device__ uint4           g_emeta[MAXE * 2];
__device__ __align__(16) __hip_bfloat16 g_h0[MAXN * 32];
__device__ __align__(16) __hip_bfloat16 g_h1[MAXN * 32];
__device__ __align__(16) __hip_bfloat16 g_h2[MAXN * 64];
__device__ __align__(16) __hip_bfloat16 g_h3[MAXN * 96];
__device__ __align__(16) __hip_bfloat16 g_Z[(size_t)MAXN * 896];
__device__ __align__(16) __hip_bfloat16 g_Wp1[28672];
__device__ __align__(16) __hip_bfloat16 g_Wp2[57344];
__device__ __align__(16) __hip_bfloat16 g_Wp3[86016];
__device__ float           g_stats[128];
__device__ int             g_isbf16;

__device__ __forceinline__ float loadf(const void* p, int i, bool bf)
{
    return bf ? (float)((const __hip_bfloat16*)p)[i] : ((const float*)p)[i];
}
__device__ __forceinline__ float bf16f(unsigned int u)
{
    return __uint_as_float(u << 16);
}
__device__ __forceinline__ unsigned short bfbits(float f)
{
    union { __hip_bfloat16 h; unsigned short u; } cv;
    cv.h = __float2bfloat16(f);
    return cv.u;
}

// ---------------- K1: zero-init scratch + wire dtype detect ----------------
__global__ void init_detect(const unsigned int* __restrict__ x, int n)
{
    int i = blockIdx.x * blockDim.x + threadIdx.x;
    if (blockIdx.x == 0 && threadIdx.x < 64) {
        int lane = threadIdx.x;
        int cnt = 0;
        for (int k = lane; k < 256; k += 64) {
            unsigned int lo = x[k] & 0xFFFFu;
            int ex = (int)((lo >> 7) & 0xFFu);
            if (lo == 0u || (ex >= 96 && ex <= 140)) cnt++;
        }
#pragma unroll
        for (int o = 1; o < 64; o <<= 1) cnt += __shfl_xor(cnt, o, 64);
        if (lane == 0) g_isbf16 = (cnt >= 200) ? 1 : 0;
    }
    if (i < n) { g_deg[i] = 0; g_cursor[i] = 0; }
    if (i < 128) g_stats[i] = 0.0f;
}

// ---------------- weight pack helpers (device) ----------------
template <int COUT>
__device__ __forceinline__ void prep_ws_dev(const void* W, const void* root,
                                            __hip_bfloat16* Wp, int t, bool bf)
{
    int j = t & 7;
    int lane = (t >> 3) & 63;
    int rest = t >> 9;
    int kk = rest % 28;
    int nt = rest / 28;
    int k = kk * 32 + (lane >> 4) * 8 + j;
    int o = nt * 16 + (lane & 15);
    float v = (k < 864) ? loadf(W, k * COUT + o, bf)
                        : loadf(root, (k - 864) * COUT + o, bf);
    Wp[t] = __float2bfloat16(v);
}

__device__ __forceinline__ void prep_w3_dev(const void* W, const void* root,
                                            __hip_bfloat16* Wp, int t, bool bf)
{
    const int KB = 3;   // KPAD=96
    int j = t & 7;
    int lane = (t >> 3) & 63;
    int rest = t >> 9;
    int kk = rest % KB;
    int nt = rest / KB;
    int k = kk * 32 + (lane >> 4) * 8 + j;
    int ncol = nt * 16 + (lane & 15);
    int kw = ncol >> 5;
    int o = ncol & 31;
    float v = 0.0f;
    if (k < 67)
        v = (kw < 27) ? loadf(W, (kw * 67 + k) * 32 + o, bf)
                      : loadf(root, k * 32 + o, bf);
    Wp[t] = __float2bfloat16(v);
}

// ---------------- K2: degree count + cast x + pack all weights ----------------
__global__ void misc_kernel(const int* __restrict__ dst, const void* __restrict__ x,
                            const void* W1, const void* r1,
                            const void* W2, const void* r2,
                            const void* W3, const void* r3, int E, int N)
{
    int t = blockIdx.x * blockDim.x + threadIdx.x;
    const bool bf = (g_isbf16 != 0);
    if (t < E) { atomicAdd(&g_deg[dst[t]], 1); return; }
    t -= E;
    int nx = N * 32;
    if (t < nx) { g_h0[t] = __float2bfloat16(loadf(x, t, bf)); return; }
    t -= nx;
    if (t < 28672) { prep_ws_dev<32>(W1, r1, g_Wp1, t, bf); return; }
    t -= 28672;
    if (t < 57344) { prep_ws_dev<64>(W2, r2, g_Wp2, t, bf); return; }
    t -= 57344;
    if (t < 86016) { prep_w3_dev(W3, r3, g_Wp3, t, bf); return; }
}

// ---------------- K3a: per-block scan (256 elems/block) ----------------
__global__ void scan_blk(int n)
{
    __shared__ int buf[256];
    int tid = threadIdx.x;
    int i = blockIdx.x * 256 + tid;
    int v = (i < n) ? g_deg[i] : 0;
    buf[tid] = v;
    __syncthreads();
    for (int o = 1; o < 256; o <<= 1) {
        int t = (tid >= o) ? buf[tid - o] : 0;
        __syncthreads();
        buf[tid] += t;
        __syncthreads();
    }
    if (i < n) g_offs[i] = buf[tid] - v;   // block-local exclusive
    if (tid == 255) g_bsum[blockIdx.x] = buf[255];
}

// ---------------- K3b: scan of block sums (1 block; nb <= 256) ----------------
__global__ void scan_top(int nb, int n)
{
    __shared__ int buf[256];
    int tid = threadIdx.x;
    int v = (tid < nb) ? g_bsum[tid] : 0;
    buf[tid] = v;
    __syncthreads();
    for (int o = 1; o < 256; o <<= 1) {
        int t = (tid >= o) ? buf[tid - o] : 0;
        __syncthreads();
        buf[tid] += t;
        __syncthreads();
    }
    if (tid < nb) g_bsum[tid] = buf[tid] - v;   // exclusive
    if (tid == nb - 1) g_offs[n] = buf[tid];    // total = E
}

// ---------------- K3c: add block offsets ----------------
__global__ void scan_add(int n)
{
    int i = blockIdx.x * 256 + threadIdx.x;
    if (i < n) g_offs[i] += g_bsum[i >> 8];
}

// ---------------- K4: basis + CSR fill (32-B edge records) ----------------
__global__ void basis_fill(const void* __restrict__ attr,
                           const int* __restrict__ src,
                           const int* __restrict__ dst, int E)
{
    int e = blockIdx.x * blockDim.x + threadIdx.x;
    if (e >= E) return;
    const bool bf = (g_isbf16 != 0);
    float f[3];
    int lo[3];
#pragma unroll
    for (int d = 0; d < 3; ++d) {
        float a = loadf(attr, e * 3 + d, bf);
        float s = a * 3.0f;
        float l = floorf(s);
        lo[d] = (int)l;
        f[d] = s - l;
    }
    const int p3[3] = {1, 3, 9};
    unsigned int wxp0 = 0, wxp1 = 0;
    unsigned short bb[8];
#pragma unroll
    for (int b = 0; b < 8; ++b) {
        float w = 1.0f;
        int id = 0;
#pragma unroll
        for (int d = 0; d < 3; ++d) {
            int bit = (b >> d) & 1;
            w *= bit ? f[d] : (1.0f - f[d]);
            id += ((lo[d] + bit) % 3) * p3[d];
        }
        if (b < 4) wxp0 |= (unsigned int)id << (8 * b);
        else       wxp1 |= (unsigned int)id << (8 * (b - 4));
        bb[b] = bfbits(w);
    }
    int d = dst[e];
    int p = atomicAdd(&g_cursor[d], 1);
    int slot = g_offs[d] + p;
    g_emeta[slot * 2] = make_uint4(wxp0, wxp1,
                                   (unsigned int)bb[0] | ((unsigned int)bb[1] << 16),
                                   (unsigned int)bb[2] | ((unsigned int)bb[3] << 16));
    g_emeta[slot * 2 + 1] = make_uint4(
        (unsigned int)bb[4] | ((unsigned int)bb[5] << 16),
        (unsigned int)bb[6] | ((unsigned int)bb[7] << 16),
        (unsigned int)src[e], 0u);
}

// ---------------- fused conv (CIN=32), 8 nodes / 512 thr ----------------
// IN_SEL: 0 = g_h0, 1 = g_h1.  OUT_SEL: 1 = g_h1 (+ELU), 2 = g_h2 (raw).
template <int COUT, bool ELU, int IN_SEL, int OUT_SEL>
__global__ __launch_bounds__(512, 8) void fused_conv(const void* __restrict__ bias,
                                                     int N)
{
    __shared__ unsigned short Sb[8 * SP2];
    __shared__ uint4 recs[8][64];
    __shared__ float invd[8];
    int tid = threadIdx.x, wid = tid >> 6, lane = tid & 63;
    int nbase = blockIdx.x * 8;
    const bool bf = (g_isbf16 != 0);
    const unsigned short* xptr = (IN_SEL == 0) ? (const unsigned short*)g_h0
                                               : (const unsigned short*)g_h1;
    const __hip_bfloat16* Wp = (COUT == 32) ? g_Wp1 : g_Wp2;

    int n = nbase + wid;
    int m = lane & 15, quad = lane >> 4;

    // ---- phase 1: wave wid builds S row for its node via MFMA scatter-GEMM ----
    if (n < N) {
        int e0 = g_offs[n], e1 = g_offs[n + 1];
        floatx4 C00 = {}, C01 = {}, C10 = {}, C11 = {};
        uint4* myrec = &recs[wid][0];
        int bin0 = m, bin1 = m + 16;
        for (int base = e0; base < e1; base += 32) {
            int cnt = e1 - base; if (cnt > 32) cnt = 32;
            if (lane < 32) {
                uint4 v0 = make_uint4(0, 0, 0, 0), v1 = make_uint4(0, 0, 0, 0);
                if (lane < cnt) {
                    size_t le = (size_t)(base + lane) * 2;
                    v0 = g_emeta[le];
                    v1 = g_emeta[le + 1];
                }
                myrec[2 * lane] = v0;
                myrec[2 * lane + 1] = v1;
            }
            // drain this wave's outstanding DS writes before the read-back:
            // intra-wave write->read ordering is NOT assumed (r15 flaked).
            __builtin_amdgcn_s_waitcnt(0);
            unsigned a0w[4] = {0, 0, 0, 0}, a1w[4] = {0, 0, 0, 0};
            unsigned b0w[4] = {0, 0, 0, 0}, b1w[4] = {0, 0, 0, 0};
#pragma unroll
            for (int j = 0; j < 8; ++j) {
                int kidx = quad * 8 + j;
                uint4 ra = myrec[2 * kidx];                       // wx03,wx47,bas01,bas23
                uint2 rb = *(const uint2*)&myrec[2 * kidx + 1];   // bas45,bas67
                int sn = (int)((const unsigned*)&myrec[2 * kidx + 1])[2];
                unsigned av0 = xptr[(size_t)sn * 32 + m];
                unsigned av1 = xptr[(size_t)sn * 32 + 16 + m];
                unsigned p0 = 0, p1 = 0;
#pragma unroll
                for (int b = 0; b < 8; ++b) {
                    unsigned wx = ((b < 4 ? ra.x : ra.y) >> (8 * (b & 3))) & 0xFFu;
                    unsigned basw = (b < 2) ? ra.z : (b < 4) ? ra.w
                                  : (b < 6) ? rb.x : rb.y;
                    unsigned bas = (b & 1) ? (basw >> 16) : (basw & 0xFFFFu);
                    if (wx == (unsigned)bin0) p0 = bas;
                    if (wx == (unsigned)bin1) p1 = bas;
                }
                unsigned sh = 16 * (j & 1);
                a0w[j >> 1] |= av0 << sh;
                a1w[j >> 1] |= av1 << sh;
                b0w[j >> 1] |= p0 << sh;
                b1w[j >> 1] |= p1 << sh;
            }
            union U { unsigned w[4]; short8 v; } A0, A1, B0, B1;
#pragma unroll
            for (int q = 0; q < 4; ++q) {
                A0.w[q] = a0w[q]; A1.w[q] = a1w[q];
                B0.w[q] = b0w[q]; B1.w[q] = b1w[q];
            }
            C00 = __builtin_amdgcn_mfma_f32_16x16x32_bf16(A0.v, B0.v, C00, 0, 0, 0);
            C01 = __builtin_amdgcn_mfma_f32_16x16x32_bf16(A0.v, B1.v, C01, 0, 0, 0);
            C10 = __builtin_amdgcn_mfma_f32_16x16x32_bf16(A1.v, B0.v, C10, 0, 0, 0);
            C11 = __builtin_amdgcn_mfma_f32_16x16x32_bf16(A1.v, B1.v, C11, 0, 0, 0);
        }
        // writeback: C[mt][nt] lane holds col=m (bin-in-tile), rows quad*4+r (ch)
        unsigned short* Srow = Sb + wid * SP2;
        {
            floatx4 Cf[4] = {C00, C01, C10, C11};
#pragma unroll
            for (int f = 0; f < 4; ++f) {
                int mt = f >> 1, nt = f & 1;
                int bin = nt * 16 + m;
                if (bin < 27) {
                    union { unsigned short h[4]; uint2 u; } pk;
#pragma unroll
                    for (int r = 0; r < 4; ++r) pk.h[r] = bfbits(Cf[f][r]);
                    *(uint2*)(Srow + bin * 32 + mt * 16 + quad * 4) = pk.u;
                }
            }
        }
        if (lane < 32) Srow[864 + lane] = xptr[(size_t)n * 32 + lane];
        if (lane == 0) {
            int deg = e1 - e0;
            invd[wid] = 1.0f / (float)(deg < 1 ? 1 : deg);
        }
    }
    __syncthreads();

    // ---- phase 2: wave w = col-tile w of GEMM 16 x 896 @ 896 x COUT ----
    if (wid * 16 < COUT) {
        int mrow = m & 7;   // 8 nodes; rows 8..15 duplicate (discarded below)
        const unsigned short* Ab = Sb + mrow * SP2 + quad * 8;
        floatx4 accS = {}, accR = {};
#pragma unroll
        for (int kk = 0; kk < 28; ++kk) {
            short8 a = *(const short8*)(Ab + kk * 32);
            const short* bp = (const short*)Wp +
                ((size_t)(wid * 28 + kk) * 64 + lane) * 8;
            short8 b = *(const short8*)bp;
            if (kk < 27) accS = __builtin_amdgcn_mfma_f32_16x16x32_bf16(a, b, accS, 0, 0, 0);
            else         accR = __builtin_amdgcn_mfma_f32_16x16x32_bf16(a, b, accR, 0, 0, 0);
        }
        int o = wid * 16 + m;
        float bval = loadf(bias, o, bf);
#pragma unroll
        for (int r = 0; r < 4; ++r) {
            int slot = quad * 4 + r;
            if (slot >= 8) continue;
            int nn = nbase + slot;
            if (nn >= N) continue;
            float v = accS[r] * invd[slot] + accR[r] + bval;
            if (ELU) v = v > 0.0f ? v : expm1f(v);
            if (OUT_SEL == 1) g_h1[nn * 32 + o] = __float2bfloat16(v);
            else              g_h2[nn * 64 + o] = __float2bfloat16(v);
        }
    }
}

// ---------------- BN stats (reads g_h2) ----------------
__global__ void bn_reduce(int n)
{
    int tid = threadIdx.x;
    int c = tid & 63;
    int r = tid >> 6;
    float s = 0.0f, s2 = 0.0f;
    for (int i = blockIdx.x * 4 + r; i < n; i += gridDim.x * 4) {
        float v = (float)g_h2[i * 64 + c];
        s += v; s2 += v * v;
    }
    __shared__ float b1s[256], b2s[256];
    b1s[tid] = s; b2s[tid] = s2;
    __syncthreads();
    if (r == 0) {
        s  = b1s[c] + b1s[c + 64] + b1s[c + 128] + b1s[c + 192];
        s2 = b2s[c] + b2s[c + 64] + b2s[c + 128] + b2s[c + 192];
        atomicAdd(&g_stats[c], s);
        atomicAdd(&g_stats[64 + c], s2);
    }
}

// ---------------- h3 = [elu(bn(h2)), pos, 0-pad] (96 ch), coef inline -------
__global__ void h3_build(const void* __restrict__ pos,
                         const void* __restrict__ gamma,
                         const void* __restrict__ beta, int N)
{
    __shared__ float cf[128];
    int t = threadIdx.x;
    const bool bf = (g_isbf16 != 0);
    if (t < 64) {
        float inv_n = 1.0f / (float)N;
        float mu = g_stats[t] * inv_n;
        float var = g_stats[64 + t] * inv_n - mu * mu;
        float A = rsqrtf(var + EPS) * loadf(gamma, t, bf);
        cf[t] = A;
        cf[64 + t] = loadf(beta, t, bf) - mu * A;
    }
    __syncthreads();
    int idx = blockIdx.x * blockDim.x + t;
    if (idx >= N * 96) return;
    int n = idx / 96, ch = idx - n * 96;
    float v;
    if (ch < 64) {
        float h = (float)g_h2[n * 64 + ch];
        v = h * cf[ch] + cf[64 + ch];
        v = v > 0.0f ? v : expm1f(v);
    } else if (ch < 67) {
        v = loadf(pos, n * 3 + (ch - 64), bf);
    } else {
        v = 0.0f;
    }
    g_h3[(size_t)n * 96 + ch] = __float2bfloat16(v);
}

// ---------------- conv3 Z-path: dense GEMM Z = h3 @ Wp3 ----------------
template <int STRIDE, int NTOT, int KPAD, int NPW>
__global__ __launch_bounds__(256) void gemm_kernel(int MT, int NTW)
{
    int gid = blockIdx.x * 256 + threadIdx.x;
    int gw = gid >> 6, lane = gid & 63;
    if (gw >= MT * NTW) return;
    int mt = gw % MT;
    int ntb = (gw / MT) * NPW;
    int m = lane & 15, quad = lane >> 4;
    const short* hrow = (const short*)g_h3 + (size_t)(mt * 16 + m) * STRIDE;
    floatx4 acc[NPW] = {};
    const int KB = KPAD / 32;
#pragma unroll
    for (int kk = 0; kk < KB; ++kk) {
        short8 a = *(const short8*)(hrow + kk * 32 + quad * 8);
#pragma unroll
        for (int i = 0; i < NPW; ++i) {
            const short* bp = (const short*)g_Wp3 +
                (((size_t)(ntb + i) * KB + kk) * 64 + lane) * 8;
            short8 b = *(const short8*)bp;
            acc[i] = __builtin_amdgcn_mfma_f32_16x16x32_bf16(a, b, acc[i], 0, 0, 0);
        }
    }
    int col = lane & 15;
    int rowbase = mt * 16 + quad * 4;
#pragma unroll
    for (int i = 0; i < NPW; ++i) {
        int ncol = (ntb + i) * 16 + col;
#pragma unroll
        for (int r = 0; r < 4; ++r)
            g_Z[(size_t)(rowbase + r) * NTOT + ncol] = __float2bfloat16(acc[i][r]);
    }
}

// ---------------- conv3: shfl gather-aggregate (COUT=32) ----------------
template <int COUT, int NTOT>
__global__ __launch_bounds__(256) void agg_kernel(const void* __restrict__ bias,
                                                  void* __restrict__ out_ext, int N)
{
    int wid = threadIdx.x >> 6, lane = threadIdx.x & 63;
    int n = blockIdx.x * 4 + wid;
    if (n >= N) return;
    const bool bf = (g_isbf16 != 0);
    const unsigned short* zp = (const unsigned short*)g_Z;
    int e0 = g_offs[n], e1 = g_offs[n + 1];
    float acc = 0.0f;
    int o = lane & 31, bh = lane >> 5;
    for (int base = e0; base < e1; base += 32) {
        int cnt = e1 - base; if (cnt > 32) cnt = 32;
        uint4 r0 = make_uint4(0, 0, 0, 0), r1 = make_uint4(0, 0, 0, 0);
        if ((lane & 31) < cnt) {
            size_t le = (size_t)(base + (lane & 31)) * 2;
            r0 = g_emeta[le];
            r1 = g_emeta[le + 1];
        }
        // layout: r0 = wx03,wx47,bas01,bas23 ; r1 = bas45,bas67,src,0
        int selw4 = (int)(bh ? r0.y : r0.x);
        int selba = (int)(bh ? r1.x : r0.z);
        int selbb = (int)(bh ? r1.y : r0.w);
        int srcv  = (int)r1.z;
#pragma unroll 2
        for (int j = 0; j < cnt; ++j) {
            int sl = j + (bh << 5);
            int sn = __shfl(srcv, j, 64);
            unsigned int w4  = (unsigned int)__shfl(selw4, sl, 64);
            unsigned int ba  = (unsigned int)__shfl(selba, sl, 64);
            unsigned int bbv = (unsigned int)__shfl(selbb, sl, 64);
            const unsigned short* zr = zp + (size_t)sn * NTOT;
#pragma unroll
            for (int bi = 0; bi < 4; ++bi) {
                int wxv = (int)((w4 >> (8 * bi)) & 0xFFu);
                unsigned int bbits = (((bi & 2) ? bbv : ba) >> (16 * (bi & 1))) & 0xFFFFu;
                acc += bf16f(bbits) * bf16f(zr[wxv * 32 + o]);
            }
        }
    }
    acc += __shfl_xor(acc, 32, 64);
    if (lane >= 32) return;
    int deg = e1 - e0;
    float inv = 1.0f / (float)(deg < 1 ? 1 : deg);
    float v = acc * inv + bf16f(zp[(size_t)n * NTOT + 27 * COUT + o])
            + loadf(bias, o, bf);
    if (bf) ((__hip_bfloat16*)out_ext)[n * COUT + o] = __float2bfloat16(v);
    else    ((float*)out_ext)[n * COUT + o] = v;
}

extern "C" void kernel_launch(void* const* d_in, const int* in_sizes, int n_in,
                              void* d_out, int out_size, void* d_ws, size_t ws_size,
                              hipStream_t stream)
{
    const void* x      = d_in[0];
    const int*  eindex = (const int*)d_in[1];
    const void* eattr  = d_in[2];
    const void* pos    = d_in[3];
    const void* W1     = d_in[4];
    const void* root1  = d_in[5];
    const void* b1     = d_in[6];
    const void* W2     = d_in[7];
    const void* root2  = d_in[8];
    const void* b2     = d_in[9];
    const void* gamma  = d_in[10];
    const void* beta   = d_in[11];
    const void* W3     = d_in[12];
    const void* root3  = d_in[13];
    const void* b3     = d_in[14];
    (void)d_ws; (void)ws_size; (void)n_in; (void)out_size;

    const int N = in_sizes[0] / 32;
    const int E = in_sizes[1] / 2;
    const int* srcp = eindex;
    const int* dstp = eindex + E;

    init_detect<<<(N + 255) / 256, 256, 0, stream>>>((const unsigned int*)x, N);
    {
        int tot = E + N * 32 + 28672 + 57344 + 86016;
        misc_kernel<<<(tot + 255) / 256, 256, 0, stream>>>(
            dstp, x, W1, root1, W2, root2, W3, root3, E, N);
    }
    // two-level parallel scan
    int nb = (N + 255) / 256;   // 196 <= 256
    scan_blk<<<nb, 256, 0, stream>>>(N);
    scan_top<<<1, 256, 0, stream>>>(nb, N);
    scan_add<<<nb, 256, 0, stream>>>(N);
    basis_fill<<<(E + 255) / 256, 256, 0, stream>>>(eattr, srcp, dstp, E);

    int nb8 = (N + 7) / 8;
    fused_conv<32, true, 0, 1><<<nb8, 512, 0, stream>>>(b1, N);
    fused_conv<64, false, 1, 2><<<nb8, 512, 0, stream>>>(b2, N);
    bn_reduce<<<120, 256, 0, stream>>>(N);
    h3_build<<<(N * 96 + 255) / 256, 256, 0, stream>>>(pos, gamma, beta, N);
    {
        const int NTOT = 28 * 32, KPAD = 96, NPW = 4;
        int NTW = (NTOT / 16) / NPW;   // 14
        int MT = (N + 15) / 16;
        int waves = MT * NTW;
        gemm_kernel<96, NTOT, KPAD, NPW><<<(waves + 3) / 4, 256, 0, stream>>>(MT, NTW);
    }
    agg_kernel<32, 28 * 32><<<(N + 3) / 4, 256, 0, stream>>>(b3, d_out, N);
}

// Round 17
// 387.018 us; speedup vs baseline: 1.5976x; 1.1191x over previous
//
#include <hip/hip_runtime.h>
#include <hip/hip_bf16.h>

// SplineCNN block.
// Edge records (32 B, CSR(dst) order), word order:
//   w0=wx[0..3], w1=wx[4..7], w2=bas01, w3=bas23, w4=bas45, w5=bas67, w6=src, w7=0
// conv1/conv2 fused, 512 thr / 8 nodes, wave-per-node:
//   Phase 1 = MFMA scatter-GEMM: S^T(32ch x 27bin) = X^T(32xK) @ P(Kx27).
//   K-slot -> edge mapping kidx = j*4 + quad (bijective K-permutation, exact):
//     - loop bound jmax = ceil(cnt/4) -> no wasted iterations at low degree
//     - record-read bank base = quad*8 -> conflict-free (r16 had 4-way, E*32)
//   Records staged per-node in LDS with s_waitcnt(0) before read-back
//   (intra-wave DS ordering NOT assumed -- r15 flaked without it).
//   S stored bf16 (pitch 904). Phase 2: MFMA GEMM, A = 28 ds_read_b128,
//   accS/accR split, invd scaling in epilogue.
// conv3: Z-scheme dense MFMA GEMM + shfl gather-aggregate.
// Scan: two-level parallel (196-block partial + top + add).

#define EPS 1e-5f
#define MAXN 50176
#define MAXE 401408
#define SP2 904   // bf16 elems per S row: 864 spline + 32 root + 8 pad

typedef __attribute__((ext_vector_type(8))) short short8;
typedef __attribute__((ext_vector_type(4))) float floatx4;

__device__ int             g_deg[MAXN];
__device__ int             g_offs[MAXN + 1];
__device__ int             g_cursor[MAXN];
__device__ int             g_bsum[256];
__device__ uint4           g_emeta[MAXE * 2];
__device__ __align__(16) __hip_bfloat16 g_h0[MAXN * 32];
__device__ __align__(16) __hip_bfloat16 g_h1[MAXN * 32];
__device__ __align__(16) __hip_bfloat16 g_h2[MAXN * 64];
__device__ __align__(16) __hip_bfloat16 g_h3[MAXN * 96];
__device__ __align__(16) __hip_bfloat16 g_Z[(size_t)MAXN * 896];
__device__ __align__(16) __hip_bfloat16 g_Wp1[28672];
__device__ __align__(16) __hip_bfloat16 g_Wp2[57344];
__device__ __align__(16) __hip_bfloat16 g_Wp3[86016];
__device__ float           g_stats[128];
__device__ int             g_isbf16;

__device__ __forceinline__ float loadf(const void* p, int i, bool bf)
{
    return bf ? (float)((const __hip_bfloat16*)p)[i] : ((const float*)p)[i];
}
__device__ __forceinline__ float bf16f(unsigned int u)
{
    return __uint_as_float(u << 16);
}
__device__ __forceinline__ unsigned short bfbits(float f)
{
    union { __hip_bfloat16 h; unsigned short u; } cv;
    cv.h = __float2bfloat16(f);
    return cv.u;
}

// ---------------- K1: zero-init scratch + wire dtype detect ----------------
__global__ void init_detect(const unsigned int* __restrict__ x, int n)
{
    int i = blockIdx.x * blockDim.x + threadIdx.x;
    if (blockIdx.x == 0 && threadIdx.x < 64) {
        int lane = threadIdx.x;
        int cnt = 0;
        for (int k = lane; k < 256; k += 64) {
            unsigned int lo = x[k] & 0xFFFFu;
            int ex = (int)((lo >> 7) & 0xFFu);
            if (lo == 0u || (ex >= 96 && ex <= 140)) cnt++;
        }
#pragma unroll
        for (int o = 1; o < 64; o <<= 1) cnt += __shfl_xor(cnt, o, 64);
        if (lane == 0) g_isbf16 = (cnt >= 200) ? 1 : 0;
    }
    if (i < n) { g_deg[i] = 0; g_cursor[i] = 0; }
    if (i < 128) g_stats[i] = 0.0f;
}

// ---------------- weight pack helpers (device) ----------------
template <int COUT>
__device__ __forceinline__ void prep_ws_dev(const void* W, const void* root,
                                            __hip_bfloat16* Wp, int t, bool bf)
{
    int j = t & 7;
    int lane = (t >> 3) & 63;
    int rest = t >> 9;
    int kk = rest % 28;
    int nt = rest / 28;
    int k = kk * 32 + (lane >> 4) * 8 + j;
    int o = nt * 16 + (lane & 15);
    float v = (k < 864) ? loadf(W, k * COUT + o, bf)
                        : loadf(root, (k - 864) * COUT + o, bf);
    Wp[t] = __float2bfloat16(v);
}

__device__ __forceinline__ void prep_w3_dev(const void* W, const void* root,
                                            __hip_bfloat16* Wp, int t, bool bf)
{
    const int KB = 3;   // KPAD=96
    int j = t & 7;
    int lane = (t >> 3) & 63;
    int rest = t >> 9;
    int kk = rest % KB;
    int nt = rest / KB;
    int k = kk * 32 + (lane >> 4) * 8 + j;
    int ncol = nt * 16 + (lane & 15);
    int kw = ncol >> 5;
    int o = ncol & 31;
    float v = 0.0f;
    if (k < 67)
        v = (kw < 27) ? loadf(W, (kw * 67 + k) * 32 + o, bf)
                      : loadf(root, k * 32 + o, bf);
    Wp[t] = __float2bfloat16(v);
}

// ---------------- K2: degree count + cast x + pack all weights ----------------
__global__ void misc_kernel(const int* __restrict__ dst, const void* __restrict__ x,
                            const void* W1, const void* r1,
                            const void* W2, const void* r2,
                            const void* W3, const void* r3, int E, int N)
{
    int t = blockIdx.x * blockDim.x + threadIdx.x;
    const bool bf = (g_isbf16 != 0);
    if (t < E) { atomicAdd(&g_deg[dst[t]], 1); return; }
    t -= E;
    int nx = N * 32;
    if (t < nx) { g_h0[t] = __float2bfloat16(loadf(x, t, bf)); return; }
    t -= nx;
    if (t < 28672) { prep_ws_dev<32>(W1, r1, g_Wp1, t, bf); return; }
    t -= 28672;
    if (t < 57344) { prep_ws_dev<64>(W2, r2, g_Wp2, t, bf); return; }
    t -= 57344;
    if (t < 86016) { prep_w3_dev(W3, r3, g_Wp3, t, bf); return; }
}

// ---------------- K3a: per-block scan (256 elems/block) ----------------
__global__ void scan_blk(int n)
{
    __shared__ int buf[256];
    int tid = threadIdx.x;
    int i = blockIdx.x * 256 + tid;
    int v = (i < n) ? g_deg[i] : 0;
    buf[tid] = v;
    __syncthreads();
    for (int o = 1; o < 256; o <<= 1) {
        int t = (tid >= o) ? buf[tid - o] : 0;
        __syncthreads();
        buf[tid] += t;
        __syncthreads();
    }
    if (i < n) g_offs[i] = buf[tid] - v;   // block-local exclusive
    if (tid == 255) g_bsum[blockIdx.x] = buf[255];
}

// ---------------- K3b: scan of block sums (1 block; nb <= 256) ----------------
__global__ void scan_top(int nb, int n)
{
    __shared__ int buf[256];
    int tid = threadIdx.x;
    int v = (tid < nb) ? g_bsum[tid] : 0;
    buf[tid] = v;
    __syncthreads();
    for (int o = 1; o < 256; o <<= 1) {
        int t = (tid >= o) ? buf[tid - o] : 0;
        __syncthreads();
        buf[tid] += t;
        __syncthreads();
    }
    if (tid < nb) g_bsum[tid] = buf[tid] - v;   // exclusive
    if (tid == nb - 1) g_offs[n] = buf[tid];    // total = E
}

// ---------------- K3c: add block offsets ----------------
__global__ void scan_add(int n)
{
    int i = blockIdx.x * 256 + threadIdx.x;
    if (i < n) g_offs[i] += g_bsum[i >> 8];
}

// ---------------- K4: basis + CSR fill (32-B edge records) ----------------
__global__ void basis_fill(const void* __restrict__ attr,
                           const int* __restrict__ src,
                           const int* __restrict__ dst, int E)
{
    int e = blockIdx.x * blockDim.x + threadIdx.x;
    if (e >= E) return;
    const bool bf = (g_isbf16 != 0);
    float f[3];
    int lo[3];
#pragma unroll
    for (int d = 0; d < 3; ++d) {
        float a = loadf(attr, e * 3 + d, bf);
        float s = a * 3.0f;
        float l = floorf(s);
        lo[d] = (int)l;
        f[d] = s - l;
    }
    const int p3[3] = {1, 3, 9};
    unsigned int wxp0 = 0, wxp1 = 0;
    unsigned short bb[8];
#pragma unroll
    for (int b = 0; b < 8; ++b) {
        float w = 1.0f;
        int id = 0;
#pragma unroll
        for (int d = 0; d < 3; ++d) {
            int bit = (b >> d) & 1;
            w *= bit ? f[d] : (1.0f - f[d]);
            id += ((lo[d] + bit) % 3) * p3[d];
        }
        if (b < 4) wxp0 |= (unsigned int)id << (8 * b);
        else       wxp1 |= (unsigned int)id << (8 * (b - 4));
        bb[b] = bfbits(w);
    }
    int d = dst[e];
    int p = atomicAdd(&g_cursor[d], 1);
    int slot = g_offs[d] + p;
    g_emeta[slot * 2] = make_uint4(wxp0, wxp1,
                                   (unsigned int)bb[0] | ((unsigned int)bb[1] << 16),
                                   (unsigned int)bb[2] | ((unsigned int)bb[3] << 16));
    g_emeta[slot * 2 + 1] = make_uint4(
        (unsigned int)bb[4] | ((unsigned int)bb[5] << 16),
        (unsigned int)bb[6] | ((unsigned int)bb[7] << 16),
        (unsigned int)src[e], 0u);
}

// ---------------- fused conv (CIN=32), 8 nodes / 512 thr ----------------
// IN_SEL: 0 = g_h0, 1 = g_h1.  OUT_SEL: 1 = g_h1 (+ELU), 2 = g_h2 (raw).
template <int COUT, bool ELU, int IN_SEL, int OUT_SEL>
__global__ __launch_bounds__(512, 8) void fused_conv(const void* __restrict__ bias,
                                                     int N)
{
    __shared__ unsigned short Sb[8 * SP2];
    __shared__ uint4 recs[8][64];
    __shared__ float invd[8];
    int tid = threadIdx.x, wid = tid >> 6, lane = tid & 63;
    int nbase = blockIdx.x * 8;
    const bool bf = (g_isbf16 != 0);
    const unsigned short* xptr = (IN_SEL == 0) ? (const unsigned short*)g_h0
                                               : (const unsigned short*)g_h1;
    const __hip_bfloat16* Wp = (COUT == 32) ? g_Wp1 : g_Wp2;

    int n = nbase + wid;
    int m = lane & 15, quad = lane >> 4;

    // ---- phase 1: wave wid builds S row for its node via MFMA scatter-GEMM ----
    if (n < N) {
        int e0 = g_offs[n], e1 = g_offs[n + 1];
        floatx4 C00 = {}, C01 = {}, C10 = {}, C11 = {};
        uint4* myrec = &recs[wid][0];
        int bin0 = m, bin1 = m + 16;
        for (int base = e0; base < e1; base += 32) {
            int cnt = e1 - base; if (cnt > 32) cnt = 32;
            if (lane < 32) {
                uint4 v0 = make_uint4(0, 0, 0, 0), v1 = make_uint4(0, 0, 0, 0);
                if (lane < cnt) {
                    size_t le = (size_t)(base + lane) * 2;
                    v0 = g_emeta[le];
                    v1 = g_emeta[le + 1];
                }
                myrec[2 * lane] = v0;
                myrec[2 * lane + 1] = v1;
            }
            // drain this wave's outstanding DS writes before the read-back:
            // intra-wave write->read ordering is NOT assumed (r15 flaked).
            __builtin_amdgcn_s_waitcnt(0);
            int jmax = (cnt + 3) >> 2;   // wave-uniform; K-slots >= cnt are zeros
            unsigned a0w[4] = {0, 0, 0, 0}, a1w[4] = {0, 0, 0, 0};
            unsigned b0w[4] = {0, 0, 0, 0}, b1w[4] = {0, 0, 0, 0};
#pragma unroll
            for (int j = 0; j < 8; ++j) {
                if (j >= jmax) break;
                // K-permutation: fragment slot (quad, j) holds edge j*4+quad.
                // A and B share the mapping -> sum over K is exact.
                int kidx = j * 4 + quad;
                uint4 ra = myrec[2 * kidx];                       // wx03,wx47,bas01,bas23
                uint2 rb = *(const uint2*)&myrec[2 * kidx + 1];   // bas45,bas67
                int sn = (int)((const unsigned*)&myrec[2 * kidx + 1])[2];
                unsigned av0 = xptr[(size_t)sn * 32 + m];
                unsigned av1 = xptr[(size_t)sn * 32 + 16 + m];
                unsigned p0 = 0, p1 = 0;
#pragma unroll
                for (int b = 0; b < 8; ++b) {
                    unsigned wx = ((b < 4 ? ra.x : ra.y) >> (8 * (b & 3))) & 0xFFu;
                    unsigned basw = (b < 2) ? ra.z : (b < 4) ? ra.w
                                  : (b < 6) ? rb.x : rb.y;
                    unsigned bas = (b & 1) ? (basw >> 16) : (basw & 0xFFFFu);
                    if (wx == (unsigned)bin0) p0 = bas;
                    if (wx == (unsigned)bin1) p1 = bas;
                }
                unsigned sh = 16 * (j & 1);
                a0w[j >> 1] |= av0 << sh;
                a1w[j >> 1] |= av1 << sh;
                b0w[j >> 1] |= p0 << sh;
                b1w[j >> 1] |= p1 << sh;
            }
            union U { unsigned w[4]; short8 v; } A0, A1, B0, B1;
#pragma unroll
            for (int q = 0; q < 4; ++q) {
                A0.w[q] = a0w[q]; A1.w[q] = a1w[q];
                B0.w[q] = b0w[q]; B1.w[q] = b1w[q];
            }
            C00 = __builtin_amdgcn_mfma_f32_16x16x32_bf16(A0.v, B0.v, C00, 0, 0, 0);
            C01 = __builtin_amdgcn_mfma_f32_16x16x32_bf16(A0.v, B1.v, C01, 0, 0, 0);
            C10 = __builtin_amdgcn_mfma_f32_16x16x32_bf16(A1.v, B0.v, C10, 0, 0, 0);
            C11 = __builtin_amdgcn_mfma_f32_16x16x32_bf16(A1.v, B1.v, C11, 0, 0, 0);
        }
        // writeback: C[mt][nt] lane holds col=m (bin-in-tile), rows quad*4+r (ch)
        unsigned short* Srow = Sb + wid * SP2;
        {
            floatx4 Cf[4] = {C00, C01, C10, C11};
#pragma unroll
            for (int f = 0; f < 4; ++f) {
                int mt = f >> 1, nt = f & 1;
                int bin = nt * 16 + m;
                if (bin < 27) {
                    union { unsigned short h[4]; uint2 u; } pk;
#pragma unroll
                    for (int r = 0; r < 4; ++r) pk.h[r] = bfbits(Cf[f][r]);
                    *(uint2*)(Srow + bin * 32 + mt * 16 + quad * 4) = pk.u;
                }
            }
        }
        if (lane < 32) Srow[864 + lane] = xptr[(size_t)n * 32 + lane];
        if (lane == 0) {
            int deg = e1 - e0;
            invd[wid] = 1.0f / (float)(deg < 1 ? 1 : deg);
        }
    }
    __syncthreads();

    // ---- phase 2: wave w = col-tile w of GEMM 16 x 896 @ 896 x COUT ----
    if (wid * 16 < COUT) {
        int mrow = m & 7;   // 8 nodes; rows 8..15 duplicate (discarded below)
        const unsigned short* Ab = Sb + mrow * SP2 + quad * 8;
        floatx4 accS = {}, accR = {};
#pragma unroll
        for (int kk = 0; kk < 28; ++kk) {
            short8 a = *(const short8*)(Ab + kk * 32);
            const short* bp = (const short*)Wp +
                ((size_t)(wid * 28 + kk) * 64 + lane) * 8;
            short8 b = *(const short8*)bp;
            if (kk < 27) accS = __builtin_amdgcn_mfma_f32_16x16x32_bf16(a, b, accS, 0, 0, 0);
            else         accR = __builtin_amdgcn_mfma_f32_16x16x32_bf16(a, b, accR, 0, 0, 0);
        }
        int o = wid * 16 + m;
        float bval = loadf(bias, o, bf);
#pragma unroll
        for (int r = 0; r < 4; ++r) {
            int slot = quad * 4 + r;
            if (slot >= 8) continue;
            int nn = nbase + slot;
            if (nn >= N) continue;
            float v = accS[r] * invd[slot] + accR[r] + bval;
            if (ELU) v = v > 0.0f ? v : expm1f(v);
            if (OUT_SEL == 1) g_h1[nn * 32 + o] = __float2bfloat16(v);
            else              g_h2[nn * 64 + o] = __float2bfloat16(v);
        }
    }
}

// ---------------- BN stats (reads g_h2) ----------------
__global__ void bn_reduce(int n)
{
    int tid = threadIdx.x;
    int c = tid & 63;
    int r = tid >> 6;
    float s = 0.0f, s2 = 0.0f;
    for (int i = blockIdx.x * 4 + r; i < n; i += gridDim.x * 4) {
        float v = (float)g_h2[i * 64 + c];
        s += v; s2 += v * v;
    }
    __shared__ float b1s[256], b2s[256];
    b1s[tid] = s; b2s[tid] = s2;
    __syncthreads();
    if (r == 0) {
        s  = b1s[c] + b1s[c + 64] + b1s[c + 128] + b1s[c + 192];
        s2 = b2s[c] + b2s[c + 64] + b2s[c + 128] + b2s[c + 192];
        atomicAdd(&g_stats[c], s);
        atomicAdd(&g_stats[64 + c], s2);
    }
}

// ---------------- h3 = [elu(bn(h2)), pos, 0-pad] (96 ch), coef inline -------
__global__ void h3_build(const void* __restrict__ pos,
                         const void* __restrict__ gamma,
                         const void* __restrict__ beta, int N)
{
    __shared__ float cf[128];
    int t = threadIdx.x;
    const bool bf = (g_isbf16 != 0);
    if (t < 64) {
        float inv_n = 1.0f / (float)N;
        float mu = g_stats[t] * inv_n;
        float var = g_stats[64 + t] * inv_n - mu * mu;
        float A = rsqrtf(var + EPS) * loadf(gamma, t, bf);
        cf[t] = A;
        cf[64 + t] = loadf(beta, t, bf) - mu * A;
    }
    __syncthreads();
    int idx = blockIdx.x * blockDim.x + t;
    if (idx >= N * 96) return;
    int n = idx / 96, ch = idx - n * 96;
    float v;
    if (ch < 64) {
        float h = (float)g_h2[n * 64 + ch];
        v = h * cf[ch] + cf[64 + ch];
        v = v > 0.0f ? v : expm1f(v);
    } else if (ch < 67) {
        v = loadf(pos, n * 3 + (ch - 64), bf);
    } else {
        v = 0.0f;
    }
    g_h3[(size_t)n * 96 + ch] = __float2bfloat16(v);
}

// ---------------- conv3 Z-path: dense GEMM Z = h3 @ Wp3 ----------------
template <int STRIDE, int NTOT, int KPAD, int NPW>
__global__ __launch_bounds__(256) void gemm_kernel(int MT, int NTW)
{
    int gid = blockIdx.x * 256 + threadIdx.x;
    int gw = gid >> 6, lane = gid & 63;
    if (gw >= MT * NTW) return;
    int mt = gw % MT;
    int ntb = (gw / MT) * NPW;
    int m = lane & 15, quad = lane >> 4;
    const short* hrow = (const short*)g_h3 + (size_t)(mt * 16 + m) * STRIDE;
    floatx4 acc[NPW] = {};
    const int KB = KPAD / 32;
#pragma unroll
    for (int kk = 0; kk < KB; ++kk) {
        short8 a = *(const short8*)(hrow + kk * 32 + quad * 8);
#pragma unroll
        for (int i = 0; i < NPW; ++i) {
            const short* bp = (const short*)g_Wp3 +
                (((size_t)(ntb + i) * KB + kk) * 64 + lane) * 8;
            short8 b = *(const short8*)bp;
            acc[i] = __builtin_amdgcn_mfma_f32_16x16x32_bf16(a, b, acc[i], 0, 0, 0);
        }
    }
    int col = lane & 15;
    int rowbase = mt * 16 + quad * 4;
#pragma unroll
    for (int i = 0; i < NPW; ++i) {
        int ncol = (ntb + i) * 16 + col;
#pragma unroll
        for (int r = 0; r < 4; ++r)
            g_Z[(size_t)(rowbase + r) * NTOT + ncol] = __float2bfloat16(acc[i][r]);
    }
}

// ---------------- conv3: shfl gather-aggregate (COUT=32) ----------------
template <int COUT, int NTOT>
__global__ __launch_bounds__(256) void agg_kernel(const void* __restrict__ bias,
                                                  void* __restrict__ out_ext, int N)
{
    int wid = threadIdx.x >> 6, lane = threadIdx.x & 63;
    int n = blockIdx.x * 4 + wid;
    if (n >= N) return;
    const bool bf = (g_isbf16 != 0);
    const unsigned short* zp = (const unsigned short*)g_Z;
    int e0 = g_offs[n], e1 = g_offs[n + 1];
    float acc = 0.0f;
    int o = lane & 31, bh = lane >> 5;
    for (int base = e0; base < e1; base += 32) {
        int cnt = e1 - base; if (cnt > 32) cnt = 32;
        uint4 r0 = make_uint4(0, 0, 0, 0), r1 = make_uint4(0, 0, 0, 0);
        if ((lane & 31) < cnt) {
            size_t le = (size_t)(base + (lane & 31)) * 2;
            r0 = g_emeta[le];
            r1 = g_emeta[le + 1];
        }
        // layout: r0 = wx03,wx47,bas01,bas23 ; r1 = bas45,bas67,src,0
        int selw4 = (int)(bh ? r0.y : r0.x);
        int selba = (int)(bh ? r1.x : r0.z);
        int selbb = (int)(bh ? r1.y : r0.w);
        int srcv  = (int)r1.z;
#pragma unroll 2
        for (int j = 0; j < cnt; ++j) {
            int sl = j + (bh << 5);
            int sn = __shfl(srcv, j, 64);
            unsigned int w4  = (unsigned int)__shfl(selw4, sl, 64);
            unsigned int ba  = (unsigned int)__shfl(selba, sl, 64);
            unsigned int bbv = (unsigned int)__shfl(selbb, sl, 64);
            const unsigned short* zr = zp + (size_t)sn * NTOT;
#pragma unroll
            for (int bi = 0; bi < 4; ++bi) {
                int wxv = (int)((w4 >> (8 * bi)) & 0xFFu);
                unsigned int bbits = (((bi & 2) ? bbv : ba) >> (16 * (bi & 1))) & 0xFFFFu;
                acc += bf16f(bbits) * bf16f(zr[wxv * 32 + o]);
            }
        }
    }
    acc += __shfl_xor(acc, 32, 64);
    if (lane >= 32) return;
    int deg = e1 - e0;
    float inv = 1.0f / (float)(deg < 1 ? 1 : deg);
    float v = acc * inv + bf16f(zp[(size_t)n * NTOT + 27 * COUT + o])
            + loadf(bias, o, bf);
    if (bf) ((__hip_bfloat16*)out_ext)[n * COUT + o] = __float2bfloat16(v);
    else    ((float*)out_ext)[n * COUT + o] = v;
}

extern "C" void kernel_launch(void* const* d_in, const int* in_sizes, int n_in,
                              void* d_out, int out_size, void* d_ws, size_t ws_size,
                              hipStream_t stream)
{
    const void* x      = d_in[0];
    const int*  eindex = (const int*)d_in[1];
    const void* eattr  = d_in[2];
    const void* pos    = d_in[3];
    const void* W1     = d_in[4];
    const void* root1  = d_in[5];
    const void* b1     = d_in[6];
    const void* W2     = d_in[7];
    const void* root2  = d_in[8];
    const void* b2     = d_in[9];
    const void* gamma  = d_in[10];
    const void* beta   = d_in[11];
    const void* W3     = d_in[12];
    const void* root3  = d_in[13];
    const void* b3     = d_in[14];
    (void)d_ws; (void)ws_size; (void)n_in; (void)out_size;

    const int N = in_sizes[0] / 32;
    const int E = in_sizes[1] / 2;
    const int* srcp = eindex;
    const int* dstp = eindex + E;

    init_detect<<<(N + 255) / 256, 256, 0, stream>>>((const unsigned int*)x, N);
    {
        int tot = E + N * 32 + 28672 + 57344 + 86016;
        misc_kernel<<<(tot + 255) / 256, 256, 0, stream>>>(
            dstp, x, W1, root1, W2, root2, W3, root3, E, N);
    }
    // two-level parallel scan
    int nb = (N + 255) / 256;   // 196 <= 256
    scan_blk<<<nb, 256, 0, stream>>>(N);
    scan_top<<<1, 256, 0, stream>>>(nb, N);
    scan_add<<<nb, 256, 0, stream>>>(N);
    basis_fill<<<(E + 255) / 256, 256, 0, stream>>>(eattr, srcp, dstp, E);

    int nb8 = (N + 7) / 8;
    fused_conv<32, true, 0, 1><<<nb8, 512, 0, stream>>>(b1, N);
    fused_conv<64, false, 1, 2><<<nb8, 512, 0, stream>>>(b2, N);
    bn_reduce<<<120, 256, 0, stream>>>(N);
    h3_build<<<(N * 96 + 255) / 256, 256, 0, stream>>>(pos, gamma, beta, N);
    {
        const int NTOT = 28 * 32, KPAD = 96, NPW = 4;
        int NTW = (NTOT / 16) / NPW;   // 14
        int MT = (N + 15) / 16;
        int waves = MT * NTW;
        gemm_kernel<96, NTOT, KPAD, NPW><<<(waves + 3) / 4, 256, 0, stream>>>(MT, NTW);
    }
    agg_kernel<32, 28 * 32><<<(N + 3) / 4, 256, 0, stream>>>(b3, d_out, N);
}

// Round 18
// 367.448 us; speedup vs baseline: 1.6827x; 1.0533x over previous
//
#include <hip/hip_runtime.h>
#include <hip/hip_bf16.h>

// SplineCNN block.
// Edge records (32 B, CSR(dst) order), word order:
//   w0=wx[0..3], w1=wx[4..7], w2=bas01, w3=bas23, w4=bas45, w5=bas67, w6=src, w7=0
// conv1/conv2 fused, 512 thr / 8 nodes, wave-per-node:
//   Phase 1 = MFMA scatter-GEMM with K-slot mapping kidx = j*4 + quad
//   (early-exit at jmax = ceil(cnt/4), conflict-free record reads).
//   s_waitcnt(0) between record staging writes and read-back (r15 flake).
//   S stored bf16 (pitch 904). Phase 2: MFMA GEMM, A = 28 ds_read_b128,
//   accS/accR split, invd scaling in epilogue.
// conv3: Z-scheme dense MFMA GEMM (col-group-major wave swizzle: the 14
//   col-groups sharing one h3 row are dispatch-adjacent -> h3 read once, not
//   14x; r17 FETCH 80 MB -> ~12 MB) + shfl gather-aggregate.
// Scan: two-level parallel (196-block partial + top + add).

#define EPS 1e-5f
#define MAXN 50176
#define MAXE 401408
#define SP2 904   // bf16 elems per S row: 864 spline + 32 root + 8 pad

typedef __attribute__((ext_vector_type(8))) short short8;
typedef __attribute__((ext_vector_type(4))) float floatx4;

__device__ int             g_deg[MAXN];
__device__ int             g_offs[MAXN + 1];
__device__ int             g_cursor[MAXN];
__device__ int             g_bsum[256];
__device__ uint4           g_emeta[MAXE * 2];
__device__ __align__(16) __hip_bfloat16 g_h0[MAXN * 32];
__device__ __align__(16) __hip_bfloat16 g_h1[MAXN * 32];
__device__ __align__(16) __hip_bfloat16 g_h2[MAXN * 64];
__device__ __align__(16) __hip_bfloat16 g_h3[MAXN * 96];
__device__ __align__(16) __hip_bfloat16 g_Z[(size_t)MAXN * 896];
__device__ __align__(16) __hip_bfloat16 g_Wp1[28672];
__device__ __align__(16) __hip_bfloat16 g_Wp2[57344];
__device__ __align__(16) __hip_bfloat16 g_Wp3[86016];
__device__ float           g_stats[128];
__device__ int             g_isbf16;

__device__ __forceinline__ float loadf(const void* p, int i, bool bf)
{
    return bf ? (float)((const __hip_bfloat16*)p)[i] : ((const float*)p)[i];
}
__device__ __forceinline__ float bf16f(unsigned int u)
{
    return __uint_as_float(u << 16);
}
__device__ __forceinline__ unsigned short bfbits(float f)
{
    union { __hip_bfloat16 h; unsigned short u; } cv;
    cv.h = __float2bfloat16(f);
    return cv.u;
}

// ---------------- K1: zero-init scratch + wire dtype detect ----------------
__global__ void init_detect(const unsigned int* __restrict__ x, int n)
{
    int i = blockIdx.x * blockDim.x + threadIdx.x;
    if (blockIdx.x == 0 && threadIdx.x < 64) {
        int lane = threadIdx.x;
        int cnt = 0;
        for (int k = lane; k < 256; k += 64) {
            unsigned int lo = x[k] & 0xFFFFu;
            int ex = (int)((lo >> 7) & 0xFFu);
            if (lo == 0u || (ex >= 96 && ex <= 140)) cnt++;
        }
#pragma unroll
        for (int o = 1; o < 64; o <<= 1) cnt += __shfl_xor(cnt, o, 64);
        if (lane == 0) g_isbf16 = (cnt >= 200) ? 1 : 0;
    }
    if (i < n) { g_deg[i] = 0; g_cursor[i] = 0; }
    if (i < 128) g_stats[i] = 0.0f;
}

// ---------------- weight pack helpers (device) ----------------
template <int COUT>
__device__ __forceinline__ void prep_ws_dev(const void* W, const void* root,
                                            __hip_bfloat16* Wp, int t, bool bf)
{
    int j = t & 7;
    int lane = (t >> 3) & 63;
    int rest = t >> 9;
    int kk = rest % 28;
    int nt = rest / 28;
    int k = kk * 32 + (lane >> 4) * 8 + j;
    int o = nt * 16 + (lane & 15);
    float v = (k < 864) ? loadf(W, k * COUT + o, bf)
                        : loadf(root, (k - 864) * COUT + o, bf);
    Wp[t] = __float2bfloat16(v);
}

__device__ __forceinline__ void prep_w3_dev(const void* W, const void* root,
                                            __hip_bfloat16* Wp, int t, bool bf)
{
    const int KB = 3;   // KPAD=96
    int j = t & 7;
    int lane = (t >> 3) & 63;
    int rest = t >> 9;
    int kk = rest % KB;
    int nt = rest / KB;
    int k = kk * 32 + (lane >> 4) * 8 + j;
    int ncol = nt * 16 + (lane & 15);
    int kw = ncol >> 5;
    int o = ncol & 31;
    float v = 0.0f;
    if (k < 67)
        v = (kw < 27) ? loadf(W, (kw * 67 + k) * 32 + o, bf)
                      : loadf(root, k * 32 + o, bf);
    Wp[t] = __float2bfloat16(v);
}

// ---------------- K2: degree count + cast x + pack all weights ----------------
__global__ void misc_kernel(const int* __restrict__ dst, const void* __restrict__ x,
                            const void* W1, const void* r1,
                            const void* W2, const void* r2,
                            const void* W3, const void* r3, int E, int N)
{
    int t = blockIdx.x * blockDim.x + threadIdx.x;
    const bool bf = (g_isbf16 != 0);
    if (t < E) { atomicAdd(&g_deg[dst[t]], 1); return; }
    t -= E;
    int nx = N * 32;
    if (t < nx) { g_h0[t] = __float2bfloat16(loadf(x, t, bf)); return; }
    t -= nx;
    if (t < 28672) { prep_ws_dev<32>(W1, r1, g_Wp1, t, bf); return; }
    t -= 28672;
    if (t < 57344) { prep_ws_dev<64>(W2, r2, g_Wp2, t, bf); return; }
    t -= 57344;
    if (t < 86016) { prep_w3_dev(W3, r3, g_Wp3, t, bf); return; }
}

// ---------------- K3a: per-block scan (256 elems/block) ----------------
__global__ void scan_blk(int n)
{
    __shared__ int buf[256];
    int tid = threadIdx.x;
    int i = blockIdx.x * 256 + tid;
    int v = (i < n) ? g_deg[i] : 0;
    buf[tid] = v;
    __syncthreads();
    for (int o = 1; o < 256; o <<= 1) {
        int t = (tid >= o) ? buf[tid - o] : 0;
        __syncthreads();
        buf[tid] += t;
        __syncthreads();
    }
    if (i < n) g_offs[i] = buf[tid] - v;   // block-local exclusive
    if (tid == 255) g_bsum[blockIdx.x] = buf[255];
}

// ---------------- K3b: scan of block sums (1 block; nb <= 256) ----------------
__global__ void scan_top(int nb, int n)
{
    __shared__ int buf[256];
    int tid = threadIdx.x;
    int v = (tid < nb) ? g_bsum[tid] : 0;
    buf[tid] = v;
    __syncthreads();
    for (int o = 1; o < 256; o <<= 1) {
        int t = (tid >= o) ? buf[tid - o] : 0;
        __syncthreads();
        buf[tid] += t;
        __syncthreads();
    }
    if (tid < nb) g_bsum[tid] = buf[tid] - v;   // exclusive
    if (tid == nb - 1) g_offs[n] = buf[tid];    // total = E
}

// ---------------- K3c: add block offsets ----------------
__global__ void scan_add(int n)
{
    int i = blockIdx.x * 256 + threadIdx.x;
    if (i < n) g_offs[i] += g_bsum[i >> 8];
}

// ---------------- K4: basis + CSR fill (32-B edge records) ----------------
__global__ void basis_fill(const void* __restrict__ attr,
                           const int* __restrict__ src,
                           const int* __restrict__ dst, int E)
{
    int e = blockIdx.x * blockDim.x + threadIdx.x;
    if (e >= E) return;
    const bool bf = (g_isbf16 != 0);
    float f[3];
    int lo[3];
#pragma unroll
    for (int d = 0; d < 3; ++d) {
        float a = loadf(attr, e * 3 + d, bf);
        float s = a * 3.0f;
        float l = floorf(s);
        lo[d] = (int)l;
        f[d] = s - l;
    }
    const int p3[3] = {1, 3, 9};
    unsigned int wxp0 = 0, wxp1 = 0;
    unsigned short bb[8];
#pragma unroll
    for (int b = 0; b < 8; ++b) {
        float w = 1.0f;
        int id = 0;
#pragma unroll
        for (int d = 0; d < 3; ++d) {
            int bit = (b >> d) & 1;
            w *= bit ? f[d] : (1.0f - f[d]);
            id += ((lo[d] + bit) % 3) * p3[d];
        }
        if (b < 4) wxp0 |= (unsigned int)id << (8 * b);
        else       wxp1 |= (unsigned int)id << (8 * (b - 4));
        bb[b] = bfbits(w);
    }
    int d = dst[e];
    int p = atomicAdd(&g_cursor[d], 1);
    int slot = g_offs[d] + p;
    g_emeta[slot * 2] = make_uint4(wxp0, wxp1,
                                   (unsigned int)bb[0] | ((unsigned int)bb[1] << 16),
                                   (unsigned int)bb[2] | ((unsigned int)bb[3] << 16));
    g_emeta[slot * 2 + 1] = make_uint4(
        (unsigned int)bb[4] | ((unsigned int)bb[5] << 16),
        (unsigned int)bb[6] | ((unsigned int)bb[7] << 16),
        (unsigned int)src[e], 0u);
}

// ---------------- fused conv (CIN=32), 8 nodes / 512 thr ----------------
// IN_SEL: 0 = g_h0, 1 = g_h1.  OUT_SEL: 1 = g_h1 (+ELU), 2 = g_h2 (raw).
template <int COUT, bool ELU, int IN_SEL, int OUT_SEL>
__global__ __launch_bounds__(512, 8) void fused_conv(const void* __restrict__ bias,
                                                     int N)
{
    __shared__ unsigned short Sb[8 * SP2];
    __shared__ uint4 recs[8][64];
    __shared__ float invd[8];
    int tid = threadIdx.x, wid = tid >> 6, lane = tid & 63;
    int nbase = blockIdx.x * 8;
    const bool bf = (g_isbf16 != 0);
    const unsigned short* xptr = (IN_SEL == 0) ? (const unsigned short*)g_h0
                                               : (const unsigned short*)g_h1;
    const __hip_bfloat16* Wp = (COUT == 32) ? g_Wp1 : g_Wp2;

    int n = nbase + wid;
    int m = lane & 15, quad = lane >> 4;

    // ---- phase 1: wave wid builds S row for its node via MFMA scatter-GEMM ----
    if (n < N) {
        int e0 = g_offs[n], e1 = g_offs[n + 1];
        floatx4 C00 = {}, C01 = {}, C10 = {}, C11 = {};
        uint4* myrec = &recs[wid][0];
        int bin0 = m, bin1 = m + 16;
        for (int base = e0; base < e1; base += 32) {
            int cnt = e1 - base; if (cnt > 32) cnt = 32;
            if (lane < 32) {
                uint4 v0 = make_uint4(0, 0, 0, 0), v1 = make_uint4(0, 0, 0, 0);
                if (lane < cnt) {
                    size_t le = (size_t)(base + lane) * 2;
                    v0 = g_emeta[le];
                    v1 = g_emeta[le + 1];
                }
                myrec[2 * lane] = v0;
                myrec[2 * lane + 1] = v1;
            }
            // drain this wave's outstanding DS writes before the read-back:
            // intra-wave write->read ordering is NOT assumed (r15 flaked).
            __builtin_amdgcn_s_waitcnt(0);
            int jmax = (cnt + 3) >> 2;   // wave-uniform; K-slots >= cnt are zeros
            unsigned a0w[4] = {0, 0, 0, 0}, a1w[4] = {0, 0, 0, 0};
            unsigned b0w[4] = {0, 0, 0, 0}, b1w[4] = {0, 0, 0, 0};
#pragma unroll
            for (int j = 0; j < 8; ++j) {
                if (j >= jmax) break;
                // K-permutation: fragment slot (quad, j) holds edge j*4+quad.
                int kidx = j * 4 + quad;
                uint4 ra = myrec[2 * kidx];                       // wx03,wx47,bas01,bas23
                uint2 rb = *(const uint2*)&myrec[2 * kidx + 1];   // bas45,bas67
                int sn = (int)((const unsigned*)&myrec[2 * kidx + 1])[2];
                unsigned av0 = xptr[(size_t)sn * 32 + m];
                unsigned av1 = xptr[(size_t)sn * 32 + 16 + m];
                unsigned p0 = 0, p1 = 0;
#pragma unroll
                for (int b = 0; b < 8; ++b) {
                    unsigned wx = ((b < 4 ? ra.x : ra.y) >> (8 * (b & 3))) & 0xFFu;
                    unsigned basw = (b < 2) ? ra.z : (b < 4) ? ra.w
                                  : (b < 6) ? rb.x : rb.y;
                    unsigned bas = (b & 1) ? (basw >> 16) : (basw & 0xFFFFu);
                    if (wx == (unsigned)bin0) p0 = bas;
                    if (wx == (unsigned)bin1) p1 = bas;
                }
                unsigned sh = 16 * (j & 1);
                a0w[j >> 1] |= av0 << sh;
                a1w[j >> 1] |= av1 << sh;
                b0w[j >> 1] |= p0 << sh;
                b1w[j >> 1] |= p1 << sh;
            }
            union U { unsigned w[4]; short8 v; } A0, A1, B0, B1;
#pragma unroll
            for (int q = 0; q < 4; ++q) {
                A0.w[q] = a0w[q]; A1.w[q] = a1w[q];
                B0.w[q] = b0w[q]; B1.w[q] = b1w[q];
            }
            C00 = __builtin_amdgcn_mfma_f32_16x16x32_bf16(A0.v, B0.v, C00, 0, 0, 0);
            C01 = __builtin_amdgcn_mfma_f32_16x16x32_bf16(A0.v, B1.v, C01, 0, 0, 0);
            C10 = __builtin_amdgcn_mfma_f32_16x16x32_bf16(A1.v, B0.v, C10, 0, 0, 0);
            C11 = __builtin_amdgcn_mfma_f32_16x16x32_bf16(A1.v, B1.v, C11, 0, 0, 0);
        }
        // writeback: C[mt][nt] lane holds col=m (bin-in-tile), rows quad*4+r (ch)
        unsigned short* Srow = Sb + wid * SP2;
        {
            floatx4 Cf[4] = {C00, C01, C10, C11};
#pragma unroll
            for (int f = 0; f < 4; ++f) {
                int mt = f >> 1, nt = f & 1;
                int bin = nt * 16 + m;
                if (bin < 27) {
                    union { unsigned short h[4]; uint2 u; } pk;
#pragma unroll
                    for (int r = 0; r < 4; ++r) pk.h[r] = bfbits(Cf[f][r]);
                    *(uint2*)(Srow + bin * 32 + mt * 16 + quad * 4) = pk.u;
                }
            }
        }
        if (lane < 32) Srow[864 + lane] = xptr[(size_t)n * 32 + lane];
        if (lane == 0) {
            int deg = e1 - e0;
            invd[wid] = 1.0f / (float)(deg < 1 ? 1 : deg);
        }
    }
    __syncthreads();

    // ---- phase 2: wave w = col-tile w of GEMM 16 x 896 @ 896 x COUT ----
    if (wid * 16 < COUT) {
        int mrow = m & 7;   // 8 nodes; rows 8..15 duplicate (discarded below)
        const unsigned short* Ab = Sb + mrow * SP2 + quad * 8;
        floatx4 accS = {}, accR = {};
#pragma unroll
        for (int kk = 0; kk < 28; ++kk) {
            short8 a = *(const short8*)(Ab + kk * 32);
            const short* bp = (const short*)Wp +
                ((size_t)(wid * 28 + kk) * 64 + lane) * 8;
            short8 b = *(const short8*)bp;
            if (kk < 27) accS = __builtin_amdgcn_mfma_f32_16x16x32_bf16(a, b, accS, 0, 0, 0);
            else         accR = __builtin_amdgcn_mfma_f32_16x16x32_bf16(a, b, accR, 0, 0, 0);
        }
        int o = wid * 16 + m;
        float bval = loadf(bias, o, bf);
#pragma unroll
        for (int r = 0; r < 4; ++r) {
            int slot = quad * 4 + r;
            if (slot >= 8) continue;
            int nn = nbase + slot;
            if (nn >= N) continue;
            float v = accS[r] * invd[slot] + accR[r] + bval;
            if (ELU) v = v > 0.0f ? v : expm1f(v);
            if (OUT_SEL == 1) g_h1[nn * 32 + o] = __float2bfloat16(v);
            else              g_h2[nn * 64 + o] = __float2bfloat16(v);
        }
    }
}

// ---------------- BN stats (reads g_h2) ----------------
__global__ void bn_reduce(int n)
{
    int tid = threadIdx.x;
    int c = tid & 63;
    int r = tid >> 6;
    float s = 0.0f, s2 = 0.0f;
    for (int i = blockIdx.x * 4 + r; i < n; i += gridDim.x * 4) {
        float v = (float)g_h2[i * 64 + c];
        s += v; s2 += v * v;
    }
    __shared__ float b1s[256], b2s[256];
    b1s[tid] = s; b2s[tid] = s2;
    __syncthreads();
    if (r == 0) {
        s  = b1s[c] + b1s[c + 64] + b1s[c + 128] + b1s[c + 192];
        s2 = b2s[c] + b2s[c + 64] + b2s[c + 128] + b2s[c + 192];
        atomicAdd(&g_stats[c], s);
        atomicAdd(&g_stats[64 + c], s2);
    }
}

// ---------------- h3 = [elu(bn(h2)), pos, 0-pad] (96 ch), coef inline -------
__global__ void h3_build(const void* __restrict__ pos,
                         const void* __restrict__ gamma,
                         const void* __restrict__ beta, int N)
{
    __shared__ float cf[128];
    int t = threadIdx.x;
    const bool bf = (g_isbf16 != 0);
    if (t < 64) {
        float inv_n = 1.0f / (float)N;
        float mu = g_stats[t] * inv_n;
        float var = g_stats[64 + t] * inv_n - mu * mu;
        float A = rsqrtf(var + EPS) * loadf(gamma, t, bf);
        cf[t] = A;
        cf[64 + t] = loadf(beta, t, bf) - mu * A;
    }
    __syncthreads();
    int idx = blockIdx.x * blockDim.x + t;
    if (idx >= N * 96) return;
    int n = idx / 96, ch = idx - n * 96;
    float v;
    if (ch < 64) {
        float h = (float)g_h2[n * 64 + ch];
        v = h * cf[ch] + cf[64 + ch];
        v = v > 0.0f ? v : expm1f(v);
    } else if (ch < 67) {
        v = loadf(pos, n * 3 + (ch - 64), bf);
    } else {
        v = 0.0f;
    }
    g_h3[(size_t)n * 96 + ch] = __float2bfloat16(v);
}

// ---------------- conv3 Z-path: dense GEMM Z = h3 @ Wp3 ----------------
// Wave swizzle: col-group-major so the NTW waves sharing an h3 row are
// dispatch-adjacent (L2-hot) -> h3 fetched ~once instead of NTW times.
template <int STRIDE, int NTOT, int KPAD, int NPW>
__global__ __launch_bounds__(256) void gemm_kernel(int MT, int NTW)
{
    int gid = blockIdx.x * 256 + threadIdx.x;
    int gw = gid >> 6, lane = gid & 63;
    if (gw >= MT * NTW) return;
    int mt = gw / NTW;                 // consecutive waves share mt
    int ntb = (gw % NTW) * NPW;
    int m = lane & 15, quad = lane >> 4;
    const short* hrow = (const short*)g_h3 + (size_t)(mt * 16 + m) * STRIDE;
    floatx4 acc[NPW] = {};
    const int KB = KPAD / 32;
#pragma unroll
    for (int kk = 0; kk < KB; ++kk) {
        short8 a = *(const short8*)(hrow + kk * 32 + quad * 8);
#pragma unroll
        for (int i = 0; i < NPW; ++i) {
            const short* bp = (const short*)g_Wp3 +
                (((size_t)(ntb + i) * KB + kk) * 64 + lane) * 8;
            short8 b = *(const short8*)bp;
            acc[i] = __builtin_amdgcn_mfma_f32_16x16x32_bf16(a, b, acc[i], 0, 0, 0);
        }
    }
    int col = lane & 15;
    int rowbase = mt * 16 + quad * 4;
#pragma unroll
    for (int i = 0; i < NPW; ++i) {
        int ncol = (ntb + i) * 16 + col;
#pragma unroll
        for (int r = 0; r < 4; ++r)
            g_Z[(size_t)(rowbase + r) * NTOT + ncol] = __float2bfloat16(acc[i][r]);
    }
}

// ---------------- conv3: shfl gather-aggregate (COUT=32) ----------------
template <int COUT, int NTOT>
__global__ __launch_bounds__(256) void agg_kernel(const void* __restrict__ bias,
                                                  void* __restrict__ out_ext, int N)
{
    int wid = threadIdx.x >> 6, lane = threadIdx.x & 63;
    int n = blockIdx.x * 4 + wid;
    if (n >= N) return;
    const bool bf = (g_isbf16 != 0);
    const unsigned short* zp = (const unsigned short*)g_Z;
    int e0 = g_offs[n], e1 = g_offs[n + 1];
    float acc = 0.0f;
    int o = lane & 31, bh = lane >> 5;
    for (int base = e0; base < e1; base += 32) {
        int cnt = e1 - base; if (cnt > 32) cnt = 32;
        uint4 r0 = make_uint4(0, 0, 0, 0), r1 = make_uint4(0, 0, 0, 0);
        if ((lane & 31) < cnt) {
            size_t le = (size_t)(base + (lane & 31)) * 2;
            r0 = g_emeta[le];
            r1 = g_emeta[le + 1];
        }
        // layout: r0 = wx03,wx47,bas01,bas23 ; r1 = bas45,bas67,src,0
        int selw4 = (int)(bh ? r0.y : r0.x);
        int selba = (int)(bh ? r1.x : r0.z);
        int selbb = (int)(bh ? r1.y : r0.w);
        int srcv  = (int)r1.z;
#pragma unroll 2
        for (int j = 0; j < cnt; ++j) {
            int sl = j + (bh << 5);
            int sn = __shfl(srcv, j, 64);
            unsigned int w4  = (unsigned int)__shfl(selw4, sl, 64);
            unsigned int ba  = (unsigned int)__shfl(selba, sl, 64);
            unsigned int bbv = (unsigned int)__shfl(selbb, sl, 64);
            const unsigned short* zr = zp + (size_t)sn * NTOT;
#pragma unroll
            for (int bi = 0; bi < 4; ++bi) {
                int wxv = (int)((w4 >> (8 * bi)) & 0xFFu);
                unsigned int bbits = (((bi & 2) ? bbv : ba) >> (16 * (bi & 1))) & 0xFFFFu;
                acc += bf16f(bbits) * bf16f(zr[wxv * 32 + o]);
            }
        }
    }
    acc += __shfl_xor(acc, 32, 64);
    if (lane >= 32) return;
    int deg = e1 - e0;
    float inv = 1.0f / (float)(deg < 1 ? 1 : deg);
    float v = acc * inv + bf16f(zp[(size_t)n * NTOT + 27 * COUT + o])
            + loadf(bias, o, bf);
    if (bf) ((__hip_bfloat16*)out_ext)[n * COUT + o] = __float2bfloat16(v);
    else    ((float*)out_ext)[n * COUT + o] = v;
}

extern "C" void kernel_launch(void* const* d_in, const int* in_sizes, int n_in,
                              void* d_out, int out_size, void* d_ws, size_t ws_size,
                              hipStream_t stream)
{
    const void* x      = d_in[0];
    const int*  eindex = (const int*)d_in[1];
    const void* eattr  = d_in[2];
    const void* pos    = d_in[3];
    const void* W1     = d_in[4];
    const void* root1  = d_in[5];
    const void* b1     = d_in[6];
    const void* W2     = d_in[7];
    const void* root2  = d_in[8];
    const void* b2     = d_in[9];
    const void* gamma  = d_in[10];
    const void* beta   = d_in[11];
    const void* W3     = d_in[12];
    const void* root3  = d_in[13];
    const void* b3     = d_in[14];
    (void)d_ws; (void)ws_size; (void)n_in; (void)out_size;

    const int N = in_sizes[0] / 32;
    const int E = in_sizes[1] / 2;
    const int* srcp = eindex;
    const int* dstp = eindex + E;

    init_detect<<<(N + 255) / 256, 256, 0, stream>>>((const unsigned int*)x, N);
    {
        int tot = E + N * 32 + 28672 + 57344 + 86016;
        misc_kernel<<<(tot + 255) / 256, 256, 0, stream>>>(
            dstp, x, W1, root1, W2, root2, W3, root3, E, N);
    }
    // two-level parallel scan
    int nb = (N + 255) / 256;   // 196 <= 256
    scan_blk<<<nb, 256, 0, stream>>>(N);
    scan_top<<<1, 256, 0, stream>>>(nb, N);
    scan_add<<<nb, 256, 0, stream>>>(N);
    basis_fill<<<(E + 255) / 256, 256, 0, stream>>>(eattr, srcp, dstp, E);

    int nb8 = (N + 7) / 8;
    fused_conv<32, true, 0, 1><<<nb8, 512, 0, stream>>>(b1, N);
    fused_conv<64, false, 1, 2><<<nb8, 512, 0, stream>>>(b2, N);
    bn_reduce<<<120, 256, 0, stream>>>(N);
    h3_build<<<(N * 96 + 255) / 256, 256, 0, stream>>>(pos, gamma, beta, N);
    {
        const int NTOT = 28 * 32, KPAD = 96, NPW = 4;
        int NTW = (NTOT / 16) / NPW;   // 14
        int MT = (N + 15) / 16;
        int waves = MT * NTW;
        gemm_kernel<96, NTOT, KPAD, NPW><<<(waves + 3) / 4, 256, 0, stream>>>(MT, NTW);
    }
    agg_kernel<32, 28 * 32><<<(N + 3) / 4, 256, 0, stream>>>(b3, d_out, N);
}